// Round 7
// baseline (2618.510 us; speedup 1.0000x reference)
//
#include <hip/hip_runtime.h>
#include <hip/hip_bf16.h>
#include <stdint.h>

// Problem constants: B=8,S=1024,D=1024,E=8,H=4096,top_k=2
#define TKN   8192
#define DD    1024
#define EE    8
#define HH    4096
#define TOPK  2
#define NASG  (TKN * TOPK)      // 16384 assignments
#define NSLOT 72                // >= sum_e ceil(cnt_e/256) (<= 64+7)

typedef unsigned short u16;
typedef __bf16 bf16x8 __attribute__((ext_vector_type(8)));
typedef float  f32x4  __attribute__((ext_vector_type(4)));

__device__ __forceinline__ u16 f2bf(float f) {
  __hip_bfloat16 h = __float2bfloat16(f);
  return __builtin_bit_cast(u16, h);
}

__device__ __forceinline__ void glds16(const void* g, void* l) {
  __builtin_amdgcn_global_load_lds(
      (__attribute__((address_space(1))) void*)g,
      (__attribute__((address_space(3))) void*)l, 16, 0, 0);
}

#define FENCE() asm volatile("" ::: "memory")
#define BAR()   do { FENCE(); __builtin_amdgcn_s_barrier(); FENCE(); } while (0)
#define WAITALL() asm volatile("s_waitcnt vmcnt(0) lgkmcnt(0)" ::: "memory")
#define VMCNT8() asm volatile("s_waitcnt vmcnt(8)" ::: "memory")

// ---------------- transpose + f32->bf16: [E][R][C] f32 -> [E][C][R] bf16
__global__ __launch_bounds__(256) void transpose_cvt_kernel(
    const float* __restrict__ src, u16* __restrict__ dst, int R, int C) {
  __shared__ float tile[64][33];
  int e = blockIdx.z;
  int c0 = blockIdx.x * 32, r0 = blockIdx.y * 64;
  int tx = threadIdx.x, ty = threadIdx.y;  // 32 x 8
  const float* s = src + (size_t)e * R * C;
  uint32_t* d32 = (uint32_t*)(dst + (size_t)e * R * C);
#pragma unroll
  for (int j = 0; j < 8; j++)
    tile[ty * 8 + j][tx] = s[(size_t)(r0 + ty * 8 + j) * C + c0 + tx];
  __syncthreads();
#pragma unroll
  for (int jj = 0; jj < 4; jj++) {
    int c = c0 + ty * 4 + jj;
    uint32_t lo = f2bf(tile[2 * tx][ty * 4 + jj]);
    uint32_t hi = f2bf(tile[2 * tx + 1][ty * 4 + jj]);
    d32[((size_t)c * R + r0) / 2 + tx] = lo | (hi << 16);
  }
}

// ---------------- router
__global__ __launch_bounds__(256) void router_kernel(
    const float* __restrict__ x, const float* __restrict__ noise,
    const float* __restrict__ Wg, const float* __restrict__ bg,
    const float* __restrict__ Wn, const float* __restrict__ bn,
    float* __restrict__ gating, u16* __restrict__ xb,
    int* __restrict__ sel_e, float* __restrict__ sel_g) {
  int t = blockIdx.x;
  int tid = threadIdx.x;
  float acc[16];
#pragma unroll
  for (int j = 0; j < 16; j++) acc[j] = 0.f;
  for (int i = tid; i < DD; i += 256) {
    float xv = x[(size_t)t * DD + i];
    xb[(size_t)t * DD + i] = f2bf(xv);
    const float4* g4 = (const float4*)(Wg + (size_t)i * EE);
    const float4* n4 = (const float4*)(Wn + (size_t)i * EE);
    float4 ga = g4[0], gb = g4[1];
    float4 na = n4[0], nb = n4[1];
    acc[0] += xv * ga.x;  acc[1] += xv * ga.y;  acc[2] += xv * ga.z;  acc[3] += xv * ga.w;
    acc[4] += xv * gb.x;  acc[5] += xv * gb.y;  acc[6] += xv * gb.z;  acc[7] += xv * gb.w;
    acc[8] += xv * na.x;  acc[9] += xv * na.y;  acc[10] += xv * na.z; acc[11] += xv * na.w;
    acc[12] += xv * nb.x; acc[13] += xv * nb.y; acc[14] += xv * nb.z; acc[15] += xv * nb.w;
  }
  __shared__ float red[4][16];
  int lane = tid & 63, wv = tid >> 6;
#pragma unroll
  for (int j = 0; j < 16; j++) {
    float v = acc[j];
    for (int o = 32; o > 0; o >>= 1) v += __shfl_down(v, o);
    acc[j] = v;
  }
  if (lane == 0) {
#pragma unroll
    for (int j = 0; j < 16; j++) red[wv][j] = acc[j];
  }
  __syncthreads();
  if (tid == 0) {
    float nz[EE];
#pragma unroll
    for (int e = 0; e < EE; e++) {
      float dg = red[0][e] + red[1][e] + red[2][e] + red[3][e] + bg[e];
      float dn = red[0][8 + e] + red[1][8 + e] + red[2][8 + e] + red[3][8 + e] + bn[e];
      float sp = fmaxf(dn, 0.f) + log1pf(expf(-fabsf(dn)));
      nz[e] = dg + noise[(size_t)t * EE + e] * sp;
    }
    int m1 = 0;
    for (int e = 1; e < EE; e++) if (nz[e] > nz[m1]) m1 = e;
    int m2 = (m1 == 0) ? 1 : 0;
    for (int e = 0; e < EE; e++) if (e != m1 && nz[e] > nz[m2]) m2 = e;
    float eb = expf(nz[m2] - nz[m1]);
    float den = 1.f + eb;
    float g1 = 1.f / den, g2 = eb / den;
    gating[(size_t)t * EE + m1] = g1;
    gating[(size_t)t * EE + m2] = g2;
    sel_e[t * 2] = m1; sel_e[t * 2 + 1] = m2;
    sel_g[t * 2] = g1; sel_g[t * 2 + 1] = g2;
  }
}

// ---------------- histogram + scan + slot table (1 block)
__global__ __launch_bounds__(256) void hist_scan_kernel(
    const int* __restrict__ sel_e, int* __restrict__ counts,
    int* __restrict__ offsets, int* __restrict__ cursors,
    int* __restrict__ slots) {
  __shared__ int hist[EE];
  int tid = threadIdx.x;
  if (tid < EE) hist[tid] = 0;
  __syncthreads();
  for (int i = tid; i < NASG; i += 256) atomicAdd(&hist[sel_e[i]], 1);
  __syncthreads();
  if (tid == 0) {
    int off = 0, ns = 0;
    for (int e = 0; e < EE; e++) {
      int c = hist[e];
      counts[e] = c; offsets[e] = off; cursors[e] = off; off += c;
      int nrt = (c + 255) >> 8;
      for (int rt = 0; rt < nrt; rt++) slots[ns++] = (e << 16) | rt;
    }
    for (; ns < NSLOT; ns++) slots[ns] = -1;
  }
}

// ---------------- build per-expert token lists (+ token->assignment-slot map)
__global__ __launch_bounds__(256) void build_lists_kernel(
    const int* __restrict__ sel_e, const float* __restrict__ sel_g,
    int* __restrict__ cursors, int* __restrict__ tok_list,
    float* __restrict__ gate_list, int* __restrict__ asg_of) {
  int t = blockIdx.x * 256 + threadIdx.x;
  int lane = threadIdx.x & 63;
#pragma unroll
  for (int k = 0; k < TOPK; k++) {
    int e = sel_e[t * 2 + k];
    float g = sel_g[t * 2 + k];
    for (int ee = 0; ee < EE; ee++) {
      unsigned long long m = __ballot(e == ee);
      if (m) {
        int leader = __ffsll(m) - 1;
        int base = 0;
        if (lane == leader) base = atomicAdd(&cursors[ee], __popcll(m));
        base = __shfl(base, leader);
        if (e == ee) {
          int slot = base + __popcll(m & ((1ull << lane) - 1ull));
          tok_list[slot] = t;
          gate_list[slot] = g;
          asg_of[t * 2 + k] = slot;
        }
      }
    }
  }
}

// ---------------- zero-fill non-selected expert_out rows (gate == 0 exactly)
__global__ __launch_bounds__(256) void zerofill_kernel(
    const float* __restrict__ gating, float* __restrict__ expert_out) {
  int id = blockIdx.x;              // 0 .. EE*TKN-1
  int e = id >> 13, t = id & (TKN - 1);
  if (gating[(size_t)t * EE + e] != 0.f) return;
  float4* p = (float4*)(expert_out + ((size_t)e * TKN + t) * DD);
  p[threadIdx.x] = (float4){0.f, 0.f, 0.f, 0.f};
}

// ---------------- combine (fallback path): final = expert rows sum
__global__ __launch_bounds__(256) void combine_kernel(
    const float* __restrict__ expert_out, const int* __restrict__ sel_e,
    float* __restrict__ final_out) {
  int t = blockIdx.x;
  int e1 = sel_e[2 * t], e2 = sel_e[2 * t + 1];
  const float4* r1 = (const float4*)(expert_out + ((size_t)e1 * TKN + t) * DD);
  const float4* r2 = (const float4*)(expert_out + ((size_t)e2 * TKN + t) * DD);
  float4* o = (float4*)(final_out + (size_t)t * DD);
  int i = threadIdx.x;
  float4 a = r1[i], b = r2[i];
  o[i] = (float4){a.x + b.x, a.y + b.y, a.z + b.z, a.w + b.w};
}

// ---------------- merge 4 K-partials + bias + gate -> expert rows + final
__global__ __launch_bounds__(256) void merge_combine_kernel(
    const float* __restrict__ part, const int* __restrict__ asg_of,
    const int* __restrict__ sel_e, const float* __restrict__ sel_g,
    const float* __restrict__ b2, float* __restrict__ expert_out,
    float* __restrict__ final_out) {
  int t = blockIdx.x;
  int i = threadIdx.x;
  int i1 = asg_of[2 * t], i2 = asg_of[2 * t + 1];
  int e1 = sel_e[2 * t], e2 = sel_e[2 * t + 1];
  float g1 = sel_g[2 * t], g2 = sel_g[2 * t + 1];
  float4 s1 = {0.f, 0.f, 0.f, 0.f}, s2 = {0.f, 0.f, 0.f, 0.f};
#pragma unroll
  for (int kq = 0; kq < 4; kq++) {
    float4 a = ((const float4*)(part + ((size_t)kq * NASG + i1) * DD))[i];
    float4 b = ((const float4*)(part + ((size_t)kq * NASG + i2) * DD))[i];
    s1.x += a.x; s1.y += a.y; s1.z += a.z; s1.w += a.w;
    s2.x += b.x; s2.y += b.y; s2.z += b.z; s2.w += b.w;
  }
  float4 bb1 = ((const float4*)(b2 + (size_t)e1 * DD))[i];
  float4 bb2 = ((const float4*)(b2 + (size_t)e2 * DD))[i];
  float4 y1 = {(s1.x + bb1.x) * g1, (s1.y + bb1.y) * g1, (s1.z + bb1.z) * g1, (s1.w + bb1.w) * g1};
  float4 y2 = {(s2.x + bb2.x) * g2, (s2.y + bb2.y) * g2, (s2.z + bb2.z) * g2, (s2.w + bb2.w) * g2};
  ((float4*)(expert_out + ((size_t)e1 * TKN + t) * DD))[i] = y1;
  ((float4*)(expert_out + ((size_t)e2 * TKN + t) * DD))[i] = y2;
  ((float4*)(final_out + (size_t)t * DD))[i] =
      (float4){y1.x + y2.x, y1.y + y2.y, y1.z + y2.z, y1.w + y2.w};
}

// ---------------- 256x256 / BK=64 / 8-wave grouped GEMM, reg-double-buffered
// One window per K-tile: { waitcnt(vm0,lgkm0); barrier; issue glds(t+2);
// issue 24 ds_reads for tile t+1 into the ALTERNATE register set; 64 MFMA on
// the CURRENT set }. The ds_reads execute in the LDS pipe concurrently with
// the MFMA pipe (fragments for tile t were loaded last window). One barrier
// per tile (was 8). WAR ledger: glds(t+2) [parity t] lands only after all
// waves drained R(t) reads (lgkm0+bar); R(t+1) [parity t+1] only after
// glds(t+1) completed on all waves (vm0+bar). No counted vmcnt -> no drain
// special cases.
// LDS swizzle: stored 16B chunk c of row r holds global chunk c^(r&7) —
// linear glds dest + inverse-swizzled per-lane global source (involution).
// Decode (1-D grid, kq-outer within XCD): gid -> xcd=gid&7, q=gid>>3,
// kq=q/(9<<LOGC), r=q%(9<<LOGC), slot=xcd*9+(r>>LOGC), ct=r&mask.
template<int KLOOP, int KSTRIDE, bool GATHER, int EPI, int LOGC>
__global__ __launch_bounds__(512, 1) void gemm8_kernel(
    const u16* __restrict__ A, const u16* __restrict__ Bm,
    const float* __restrict__ bias, const int* __restrict__ tok_list,
    const float* __restrict__ gate_list, const int* __restrict__ counts,
    const int* __restrict__ offsets, const int* __restrict__ slots,
    int Ncols, u16* __restrict__ OutBf, float* __restrict__ outF) {
  constexpr int NT = KLOOP / 64;
  static_assert((NT & 1) == 0, "window loop unrolled by 2");
  int gid = blockIdx.x;
  int q = gid >> 3;
  constexpr int PERX = 9 << LOGC;
  int kq = q / PERX;
  int r0q = q - kq * PERX;
  int slot = (gid & 7) * 9 + (r0q >> LOGC);
  int ct = r0q & ((1 << LOGC) - 1);
  int packed = slots[slot];
  if (packed < 0) return;
  int e = packed >> 16;
  int rt = packed & 0xffff;
  int cnt = counts[e];
  int off = offsets[e];
  int col0 = ct * 256;
  int k0e = kq * KLOOP;

  __shared__ __attribute__((aligned(16))) char ldsc[131072];  // A 64K | B 64K

  int tid = threadIdx.x;
  int w = tid >> 6, l = tid & 63;
  int wm = w >> 2, wn = w & 3;            // 2 x 4 wave grid
  int fr = l & 15, hi = l >> 4;
  int kk16 = hi << 4;
  int xr = (fr & 7) << 4;

  int rl0 = w * 8 + (l >> 3);
  int slotE = ((l & 7) ^ ((l >> 3) & 7)) << 3;  // pre-swizzled 8-elem slot
  const u16* aptr[4];
  const u16* bptr[4];
#pragma unroll
  for (int i = 0; i < 4; i++) {
    int r = rt * 256 + rl0 + i * 64;
    if (GATHER) {
      int idx = min(off + r, NASG - 1);
      aptr[i] = A + (size_t)tok_list[idx] * KSTRIDE + k0e + slotE;
    } else {
      aptr[i] = A + (size_t)(off + r) * KSTRIDE + k0e + slotE;
    }
    bptr[i] = Bm + ((size_t)e * Ncols + col0 + rl0 + i * 64) * KSTRIDE + k0e + slotE;
  }
  char* ldsA = ldsc;
  char* ldsB = ldsc + 65536;

  auto issueAB = [&](int t) {
    char* db = ldsB + (t & 1) * 32768 + w * 1024;
    char* da = ldsA + (t & 1) * 32768 + w * 1024;
    glds16(bptr[0] + t * 64, db);
    glds16(bptr[1] + t * 64, db + 8192);
    glds16(bptr[2] + t * 64, db + 16384);
    glds16(bptr[3] + t * 64, db + 24576);
    glds16(aptr[0] + t * 64, da);
    glds16(aptr[1] + t * 64, da + 8192);
    glds16(aptr[2] + t * 64, da + 16384);
    glds16(aptr[3] + t * 64, da + 24576);
  };

  f32x4 acc[8][4];
#pragma unroll
  for (int m = 0; m < 8; m++)
#pragma unroll
    for (int n = 0; n < 4; n++) acc[m][n] = (f32x4){0.f, 0.f, 0.f, 0.f};

  bf16x8 aS0[8][2], bS0[4][2], aS1[8][2], bS1[4][2];

  auto READ = [&](int p, bf16x8 (&aS)[8][2], bf16x8 (&bS)[4][2]) {
    const char* ab = ldsc + p * 32768;
    const char* bb = ldsc + 65536 + p * 32768;
#pragma unroll
    for (int mm = 0; mm < 8; mm++)
#pragma unroll
      for (int ks = 0; ks < 2; ks++)
        aS[mm][ks] = *(const bf16x8*)(ab + (wm * 128 + mm * 16 + fr) * 128 +
                                      ((ks * 64 + kk16) ^ xr));
#pragma unroll
    for (int nn = 0; nn < 4; nn++)
#pragma unroll
      for (int ks = 0; ks < 2; ks++)
        bS[nn][ks] = *(const bf16x8*)(bb + (wn * 64 + nn * 16 + fr) * 128 +
                                      ((ks * 64 + kk16) ^ xr));
  };
  auto MM = [&](bf16x8 (&aS)[8][2], bf16x8 (&bS)[4][2]) {
    __builtin_amdgcn_s_setprio(1);
#pragma unroll
    for (int mm = 0; mm < 8; mm++)
#pragma unroll
      for (int nn = 0; nn < 4; nn++)
#pragma unroll
        for (int ks = 0; ks < 2; ks++)
          acc[mm][nn] = __builtin_amdgcn_mfma_f32_16x16x32_bf16(aS[mm][ks], bS[nn][ks],
                                                                acc[mm][nn], 0, 0, 0);
    __builtin_amdgcn_s_setprio(0);
  };

  // prologue: stage tiles 0,1; fragments for tile 0
  issueAB(0);
  issueAB(1);
  VMCNT8();   // own glds(0) complete
  BAR();      // everyone's glds(0) complete
  READ(0, aS0, bS0);

  for (int t = 0; t < NT; t += 2) {
    // window t: MFMA(t) on set0 (parity 0); read tile t+1 into set1
    WAITALL();                       // drains R(t) reads + glds(t+1)
    BAR();
    if (t + 2 < NT) issueAB(t + 2);  // parity 0 (safe: R(t) drained everywhere)
    READ(1, aS1, bS1);               // parity 1 (staged: glds(t+1) done)
    MM(aS0, bS0);
    // window t+1: MFMA(t+1) on set1; read tile t+2 into set0
    WAITALL();                       // drains R(t+1) reads + glds(t+2)
    BAR();
    if (t + 3 < NT) issueAB(t + 3);  // parity 1
    if (t + 2 < NT) READ(0, aS0, bS0);  // parity 0
    MM(aS1, bS1);
  }

  // ---- epilogue
  float biasN[4];
  int cN[4];
#pragma unroll
  for (int n = 0; n < 4; n++) {
    cN[n] = col0 + wn * 64 + n * 16 + fr;
    biasN[n] = (EPI == 2) ? 0.f : bias[e * Ncols + cN[n]];
  }
  if constexpr (EPI == 0) {
#pragma unroll
    for (int m = 0; m < 8; m++) {
      int rb = rt * 256 + wm * 128 + m * 16 + hi * 4;
#pragma unroll
      for (int j = 0; j < 4; j++) {
        int r = rb + j;
        if (r < cnt) {
#pragma unroll
          for (int n = 0; n < 4; n++) {
            float v = acc[m][n][j] + biasN[n];
            OutBf[(size_t)(off + r) * Ncols + cN[n]] = f2bf(fmaxf(v, 0.f));
          }
        }
      }
    }
  } else if constexpr (EPI == 1) {
#pragma unroll
    for (int m = 0; m < 8; m++) {
      int rb = rt * 256 + wm * 128 + m * 16 + hi * 4;
#pragma unroll
      for (int j = 0; j < 4; j++) {
        int r = rb + j;
        if (r < cnt) {
          int idx = off + r;
          int tok = tok_list[idx];
          float g = gate_list[idx];
          size_t erow = ((size_t)e * TKN + tok) * DD;
#pragma unroll
          for (int n = 0; n < 4; n++)
            outF[erow + cN[n]] = (acc[m][n][j] + biasN[n]) * g;
        }
      }
    }
  } else {
    // raw K-partial: outF[kq][asg][DD]
#pragma unroll
    for (int m = 0; m < 8; m++) {
      int rb = rt * 256 + wm * 128 + m * 16 + hi * 4;
#pragma unroll
      for (int j = 0; j < 4; j++) {
        int r = rb + j;
        if (r < cnt) {
          size_t prow = ((size_t)kq * NASG + off + r) * DD;
#pragma unroll
          for (int n = 0; n < 4; n++)
            outF[prow + cN[n]] = acc[m][n][j];
        }
      }
    }
  }
}

extern "C" void kernel_launch(void* const* d_in, const int* in_sizes, int n_in,
                              void* d_out, int out_size, void* d_ws, size_t ws_size,
                              hipStream_t stream) {
  const float* x     = (const float*)d_in[0];
  const float* noise = (const float*)d_in[1];
  const float* Wg    = (const float*)d_in[2];
  const float* bg    = (const float*)d_in[3];
  const float* Wn    = (const float*)d_in[4];
  const float* bn    = (const float*)d_in[5];
  const float* W1    = (const float*)d_in[6];
  const float* b1    = (const float*)d_in[7];
  const float* W2    = (const float*)d_in[8];
  const float* b2    = (const float*)d_in[9];

  float* final_out  = (float*)d_out;
  float* expert_out = final_out + (size_t)TKN * DD;
  float* gating     = expert_out + (size_t)EE * TKN * DD;

  char* ws = (char*)d_ws;
  size_t o = 0;
  auto alloc = [&](size_t bytes) {
    char* p = ws + o;
    o += bytes;
    o = (o + 255) & ~(size_t)255;
    return p;
  };
  u16*   xb        = (u16*)alloc((size_t)TKN * DD * 2);
  u16*   w1t       = (u16*)alloc((size_t)EE * HH * DD * 2);        // [E][H][D]
  u16*   w2t       = (u16*)alloc((size_t)EE * DD * HH * 2);        // [E][D][H]
  u16*   hbuf      = (u16*)alloc(((size_t)NASG + 256) * HH * 2);   // +256 pad rows
  int*   tok_list  = (int*)alloc((size_t)NASG * 4);
  float* gate_list = (float*)alloc((size_t)NASG * 4);
  int*   sel_e     = (int*)alloc((size_t)NASG * 4);
  float* sel_g     = (float*)alloc((size_t)NASG * 4);
  int*   asg_of    = (int*)alloc((size_t)NASG * 4);
  int*   counts    = (int*)alloc(256);
  int*   offsets   = (int*)alloc(256);
  int*   cursors   = (int*)alloc(256);
  int*   slots     = (int*)alloc(NSLOT * 4);
  float* part      = (float*)alloc((size_t)4 * NASG * DD * 4);     // 268 MB (last)
  bool use_split = (o <= ws_size);

  // zero only gating (router writes just the top-2 entries per token)
  hipMemsetAsync(gating, 0, (size_t)TKN * EE * sizeof(float), stream);

  router_kernel<<<TKN, 256, 0, stream>>>(x, noise, Wg, bg, Wn, bn, gating, xb, sel_e, sel_g);
  hist_scan_kernel<<<1, 256, 0, stream>>>(sel_e, counts, offsets, cursors, slots);
  build_lists_kernel<<<TKN / 256, 256, 0, stream>>>(sel_e, sel_g, cursors, tok_list,
                                                    gate_list, asg_of);
  // zero only the non-selected expert_out rows (gate==0 <=> not selected)
  zerofill_kernel<<<EE * TKN, 256, 0, stream>>>(gating, expert_out);

  transpose_cvt_kernel<<<dim3(HH / 32, DD / 64, EE), dim3(32, 8), 0, stream>>>(W1, w1t, DD, HH);
  transpose_cvt_kernel<<<dim3(DD / 32, HH / 64, EE), dim3(32, 8), 0, stream>>>(W2, w2t, HH, DD);

  // GEMM1: h = relu(x[tok] @ W1[e] + b1), K=1024, N=4096; 16 col-tiles
  gemm8_kernel<DD, DD, true, 0, 4><<<8 * 9 * 16, 512, 0, stream>>>(
      xb, w1t, b1, tok_list, nullptr, counts, offsets, slots, HH, hbuf, nullptr);

  if (use_split) {
    // GEMM2 split-K x4: raw partials, then merge(+bias,gate)+combine per token
    gemm8_kernel<HH / 4, HH, false, 2, 2><<<8 * 9 * 4 * 4, 512, 0, stream>>>(
        hbuf, w2t, b2, tok_list, gate_list, counts, offsets, slots, DD, nullptr, part);
    merge_combine_kernel<<<TKN, 256, 0, stream>>>(part, asg_of, sel_e, sel_g, b2,
                                                  expert_out, final_out);
  } else {
    // fallback: single-shot GEMM2 + combine
    gemm8_kernel<HH, HH, false, 1, 2><<<8 * 9 * 4, 512, 0, stream>>>(
        hbuf, w2t, b2, tok_list, gate_list, counts, offsets, slots, DD, nullptr, expert_out);
    combine_kernel<<<TKN, 256, 0, stream>>>(expert_out, sel_e, final_out);
  }
}

// Round 8
// 629.421 us; speedup vs baseline: 4.1602x; 4.1602x over previous
//
#include <hip/hip_runtime.h>
#include <hip/hip_bf16.h>
#include <stdint.h>

// Problem constants: B=8,S=1024,D=1024,E=8,H=4096,top_k=2
#define TKN   8192
#define DD    1024
#define EE    8
#define HH    4096
#define TOPK  2
#define NASG  (TKN * TOPK)      // 16384 assignments
#define NSLOT 72                // >= sum_e ceil(cnt_e/256) (<= 64+7)

typedef unsigned short u16;
typedef __bf16 bf16x8 __attribute__((ext_vector_type(8)));
typedef float  f32x4  __attribute__((ext_vector_type(4)));

__device__ __forceinline__ u16 f2bf(float f) {
  __hip_bfloat16 h = __float2bfloat16(f);
  return __builtin_bit_cast(u16, h);
}
__device__ __forceinline__ float bf2f(u16 u) {
  uint32_t v = ((uint32_t)u) << 16;
  return __builtin_bit_cast(float, v);
}

__device__ __forceinline__ void glds16(const void* g, void* l) {
  __builtin_amdgcn_global_load_lds(
      (__attribute__((address_space(1))) void*)g,
      (__attribute__((address_space(3))) void*)l, 16, 0, 0);
}

#define FENCE() asm volatile("" ::: "memory")
#define BAR()   do { FENCE(); __builtin_amdgcn_s_barrier(); FENCE(); } while (0)
#define VMCNT8() asm volatile("s_waitcnt vmcnt(8)" ::: "memory")
#define VMCNT0() asm volatile("s_waitcnt vmcnt(0)" ::: "memory")

// ---------------- transpose + f32->bf16: [E][R][C] f32 -> [E][C][R] bf16
__global__ __launch_bounds__(256) void transpose_cvt_kernel(
    const float* __restrict__ src, u16* __restrict__ dst, int R, int C) {
  __shared__ float tile[64][33];
  int e = blockIdx.z;
  int c0 = blockIdx.x * 32, r0 = blockIdx.y * 64;
  int tx = threadIdx.x, ty = threadIdx.y;  // 32 x 8
  const float* s = src + (size_t)e * R * C;
  uint32_t* d32 = (uint32_t*)(dst + (size_t)e * R * C);
#pragma unroll
  for (int j = 0; j < 8; j++)
    tile[ty * 8 + j][tx] = s[(size_t)(r0 + ty * 8 + j) * C + c0 + tx];
  __syncthreads();
#pragma unroll
  for (int jj = 0; jj < 4; jj++) {
    int c = c0 + ty * 4 + jj;
    uint32_t lo = f2bf(tile[2 * tx][ty * 4 + jj]);
    uint32_t hi = f2bf(tile[2 * tx + 1][ty * 4 + jj]);
    d32[((size_t)c * R + r0) / 2 + tx] = lo | (hi << 16);
  }
}

// ---------------- router
__global__ __launch_bounds__(256) void router_kernel(
    const float* __restrict__ x, const float* __restrict__ noise,
    const float* __restrict__ Wg, const float* __restrict__ bg,
    const float* __restrict__ Wn, const float* __restrict__ bn,
    float* __restrict__ gating, u16* __restrict__ xb,
    int* __restrict__ sel_e, float* __restrict__ sel_g) {
  int t = blockIdx.x;
  int tid = threadIdx.x;
  float acc[16];
#pragma unroll
  for (int j = 0; j < 16; j++) acc[j] = 0.f;
  for (int i = tid; i < DD; i += 256) {
    float xv = x[(size_t)t * DD + i];
    xb[(size_t)t * DD + i] = f2bf(xv);
    const float4* g4 = (const float4*)(Wg + (size_t)i * EE);
    const float4* n4 = (const float4*)(Wn + (size_t)i * EE);
    float4 ga = g4[0], gb = g4[1];
    float4 na = n4[0], nb = n4[1];
    acc[0] += xv * ga.x;  acc[1] += xv * ga.y;  acc[2] += xv * ga.z;  acc[3] += xv * ga.w;
    acc[4] += xv * gb.x;  acc[5] += xv * gb.y;  acc[6] += xv * gb.z;  acc[7] += xv * gb.w;
    acc[8] += xv * na.x;  acc[9] += xv * na.y;  acc[10] += xv * na.z; acc[11] += xv * na.w;
    acc[12] += xv * nb.x; acc[13] += xv * nb.y; acc[14] += xv * nb.z; acc[15] += xv * nb.w;
  }
  __shared__ float red[4][16];
  int lane = tid & 63, wv = tid >> 6;
#pragma unroll
  for (int j = 0; j < 16; j++) {
    float v = acc[j];
    for (int o = 32; o > 0; o >>= 1) v += __shfl_down(v, o);
    acc[j] = v;
  }
  if (lane == 0) {
#pragma unroll
    for (int j = 0; j < 16; j++) red[wv][j] = acc[j];
  }
  __syncthreads();
  if (tid == 0) {
    float nz[EE];
#pragma unroll
    for (int e = 0; e < EE; e++) {
      float dg = red[0][e] + red[1][e] + red[2][e] + red[3][e] + bg[e];
      float dn = red[0][8 + e] + red[1][8 + e] + red[2][8 + e] + red[3][8 + e] + bn[e];
      float sp = fmaxf(dn, 0.f) + log1pf(expf(-fabsf(dn)));
      nz[e] = dg + noise[(size_t)t * EE + e] * sp;
    }
    int m1 = 0;
    for (int e = 1; e < EE; e++) if (nz[e] > nz[m1]) m1 = e;
    int m2 = (m1 == 0) ? 1 : 0;
    for (int e = 0; e < EE; e++) if (e != m1 && nz[e] > nz[m2]) m2 = e;
    float eb = expf(nz[m2] - nz[m1]);
    float den = 1.f + eb;
    float g1 = 1.f / den, g2 = eb / den;
    gating[(size_t)t * EE + m1] = g1;
    gating[(size_t)t * EE + m2] = g2;
    sel_e[t * 2] = m1; sel_e[t * 2 + 1] = m2;
    sel_g[t * 2] = g1; sel_g[t * 2 + 1] = g2;
  }
}

// ---------------- histogram + scan + slot table (1 block)
__global__ __launch_bounds__(256) void hist_scan_kernel(
    const int* __restrict__ sel_e, int* __restrict__ counts,
    int* __restrict__ offsets, int* __restrict__ cursors,
    int* __restrict__ slots) {
  __shared__ int hist[EE];
  int tid = threadIdx.x;
  if (tid < EE) hist[tid] = 0;
  __syncthreads();
  for (int i = tid; i < NASG; i += 256) atomicAdd(&hist[sel_e[i]], 1);
  __syncthreads();
  if (tid == 0) {
    int off = 0, ns = 0;
    for (int e = 0; e < EE; e++) {
      int c = hist[e];
      counts[e] = c; offsets[e] = off; cursors[e] = off; off += c;
      int nrt = (c + 255) >> 8;
      for (int rt = 0; rt < nrt; rt++) slots[ns++] = (e << 16) | rt;
    }
    for (; ns < NSLOT; ns++) slots[ns] = -1;
  }
}

// ---------------- build per-expert token lists (+ token->assignment-slot map)
__global__ __launch_bounds__(256) void build_lists_kernel(
    const int* __restrict__ sel_e, const float* __restrict__ sel_g,
    int* __restrict__ cursors, int* __restrict__ tok_list,
    float* __restrict__ gate_list, int* __restrict__ asg_of) {
  int t = blockIdx.x * 256 + threadIdx.x;
  int lane = threadIdx.x & 63;
#pragma unroll
  for (int k = 0; k < TOPK; k++) {
    int e = sel_e[t * 2 + k];
    float g = sel_g[t * 2 + k];
    for (int ee = 0; ee < EE; ee++) {
      unsigned long long m = __ballot(e == ee);
      if (m) {
        int leader = __ffsll(m) - 1;
        int base = 0;
        if (lane == leader) base = atomicAdd(&cursors[ee], __popcll(m));
        base = __shfl(base, leader);
        if (e == ee) {
          int slot = base + __popcll(m & ((1ull << lane) - 1ull));
          tok_list[slot] = t;
          gate_list[slot] = g;
          asg_of[t * 2 + k] = slot;
        }
      }
    }
  }
}

// ---------------- zero-fill non-selected expert_out rows (gate == 0 exactly)
__global__ __launch_bounds__(256) void zerofill_kernel(
    const float* __restrict__ gating, float* __restrict__ expert_out) {
  int id = blockIdx.x;              // 0 .. EE*TKN-1
  int e = id >> 13, t = id & (TKN - 1);
  if (gating[(size_t)t * EE + e] != 0.f) return;
  float4* p = (float4*)(expert_out + ((size_t)e * TKN + t) * DD);
  p[threadIdx.x] = (float4){0.f, 0.f, 0.f, 0.f};
}

// ---------------- combine (fallback path): final = expert rows sum
__global__ __launch_bounds__(256) void combine_kernel(
    const float* __restrict__ expert_out, const int* __restrict__ sel_e,
    float* __restrict__ final_out) {
  int t = blockIdx.x;
  int e1 = sel_e[2 * t], e2 = sel_e[2 * t + 1];
  const float4* r1 = (const float4*)(expert_out + ((size_t)e1 * TKN + t) * DD);
  const float4* r2 = (const float4*)(expert_out + ((size_t)e2 * TKN + t) * DD);
  float4* o = (float4*)(final_out + (size_t)t * DD);
  int i = threadIdx.x;
  float4 a = r1[i], b = r2[i];
  o[i] = (float4){a.x + b.x, a.y + b.y, a.z + b.z, a.w + b.w};
}

// ---------------- merge 4 bf16 K-partials + bias + gate -> expert rows + final
// thread i handles elements [4i, 4i+4) of each row.
__global__ __launch_bounds__(256) void merge_combine_kernel(
    const u16* __restrict__ part, const int* __restrict__ asg_of,
    const int* __restrict__ sel_e, const float* __restrict__ sel_g,
    const float* __restrict__ b2, float* __restrict__ expert_out,
    float* __restrict__ final_out) {
  int t = blockIdx.x;
  int i = threadIdx.x;
  int i1 = asg_of[2 * t], i2 = asg_of[2 * t + 1];
  int e1 = sel_e[2 * t], e2 = sel_e[2 * t + 1];
  float g1 = sel_g[2 * t], g2 = sel_g[2 * t + 1];
  float s1[4] = {0.f, 0.f, 0.f, 0.f}, s2[4] = {0.f, 0.f, 0.f, 0.f};
#pragma unroll
  for (int kq = 0; kq < 4; kq++) {
    ushort4 a = ((const ushort4*)(part + ((size_t)kq * NASG + i1) * DD))[i];
    ushort4 b = ((const ushort4*)(part + ((size_t)kq * NASG + i2) * DD))[i];
    s1[0] += bf2f(a.x); s1[1] += bf2f(a.y); s1[2] += bf2f(a.z); s1[3] += bf2f(a.w);
    s2[0] += bf2f(b.x); s2[1] += bf2f(b.y); s2[2] += bf2f(b.z); s2[3] += bf2f(b.w);
  }
  float4 bb1 = ((const float4*)(b2 + (size_t)e1 * DD))[i];
  float4 bb2 = ((const float4*)(b2 + (size_t)e2 * DD))[i];
  float4 y1 = {(s1[0] + bb1.x) * g1, (s1[1] + bb1.y) * g1,
               (s1[2] + bb1.z) * g1, (s1[3] + bb1.w) * g1};
  float4 y2 = {(s2[0] + bb2.x) * g2, (s2[1] + bb2.y) * g2,
               (s2[2] + bb2.z) * g2, (s2[3] + bb2.w) * g2};
  ((float4*)(expert_out + ((size_t)e1 * TKN + t) * DD))[i] = y1;
  ((float4*)(expert_out + ((size_t)e2 * TKN + t) * DD))[i] = y2;
  ((float4*)(final_out + (size_t)t * DD))[i] =
      (float4){y1.x + y2.x, y1.y + y2.y, y1.z + y2.z, y1.w + y2.w};
}

// ---------------- 256x256 / BK=64 / 8-wave grouped GEMM (round-6 core, verified)
// EPI: 0 = relu->bf16 OutBf; 1 = (acc+bias)*gate -> f32 outF (expert rows);
// 2 = bf16 K-partial -> outP[kq][asg][DD].
// Decode (1-D grid, kq-outer within XCD): gid -> xcd=gid&7, q=gid>>3,
// kq=q/(9<<LOGC), r=q%(9<<LOGC), slot=xcd*9+(r>>LOGC), ct=r&mask.
// LDS swizzle: stored 16B chunk c of row r holds global chunk c^(r&7) —
// linear glds dest + inverse-swizzled per-lane global source (involution).
// vmcnt ledger: P3 issues B(t+2), P4 issues A(t+2); at P4 16 outstanding ->
// vmcnt(8) completes B(t+1)+A(t+1). Tail t>=NT-2: vmcnt(0) full drain.
template<int KLOOP, int KSTRIDE, bool GATHER, int EPI, int LOGC>
__global__ __launch_bounds__(512, 2) void gemm8_kernel(
    const u16* __restrict__ A, const u16* __restrict__ Bm,
    const float* __restrict__ bias, const int* __restrict__ tok_list,
    const float* __restrict__ gate_list, const int* __restrict__ counts,
    const int* __restrict__ offsets, const int* __restrict__ slots,
    int Ncols, u16* __restrict__ OutBf, float* __restrict__ outF,
    u16* __restrict__ outP) {
  constexpr int NT = KLOOP / 64;
  int gid = blockIdx.x;
  int q = gid >> 3;
  constexpr int PERX = 9 << LOGC;
  int kq = q / PERX;
  int r0q = q - kq * PERX;
  int slot = (gid & 7) * 9 + (r0q >> LOGC);
  int ct = r0q & ((1 << LOGC) - 1);
  int packed = slots[slot];
  if (packed < 0) return;
  int e = packed >> 16;
  int rt = packed & 0xffff;
  int cnt = counts[e];
  int off = offsets[e];
  int col0 = ct * 256;
  int k0e = kq * KLOOP;   // element offset of this K-slice

  __shared__ __attribute__((aligned(16))) char ldsc[131072];  // A 64K | B 64K

  int tid = threadIdx.x;
  int w = tid >> 6, l = tid & 63;
  int wm = w >> 2, wn = w & 3;            // 2 x 4 wave grid
  int fr = l & 15, hi = l >> 4;
  int kk16 = hi << 4;
  int xr = (fr & 7) << 4;

  int rl0 = w * 8 + (l >> 3);
  int slotE = ((l & 7) ^ ((l >> 3) & 7)) << 3;  // pre-swizzled 8-elem slot
  const u16* aptr[4];
  const u16* bptr[4];
#pragma unroll
  for (int i = 0; i < 4; i++) {
    int r = rt * 256 + rl0 + i * 64;
    if (GATHER) {
      int idx = min(off + r, NASG - 1);
      aptr[i] = A + (size_t)tok_list[idx] * KSTRIDE + k0e + slotE;
    } else {
      aptr[i] = A + (size_t)(off + r) * KSTRIDE + k0e + slotE;
    }
    bptr[i] = Bm + ((size_t)e * Ncols + col0 + rl0 + i * 64) * KSTRIDE + k0e + slotE;
  }
  char* ldsA = ldsc;
  char* ldsB = ldsc + 65536;

  auto issueA = [&](int t, int h) {
    char* d = ldsA + (t & 1) * 32768 + h * 16384 + w * 1024;
    glds16(aptr[h * 2 + 0] + t * 64, d);
    glds16(aptr[h * 2 + 1] + t * 64, d + 8192);
  };
  auto issueB = [&](int t, int h) {
    char* d = ldsB + (t & 1) * 32768 + h * 16384 + w * 1024;
    glds16(bptr[h * 2 + 0] + t * 64, d);
    glds16(bptr[h * 2 + 1] + t * 64, d + 8192);
  };

  f32x4 acc[8][4];
#pragma unroll
  for (int m = 0; m < 8; m++)
#pragma unroll
    for (int n = 0; n < 4; n++) acc[m][n] = (f32x4){0.f, 0.f, 0.f, 0.f};
  bf16x8 aF[4][2], bF0[2][2], bF1[2][2];

  // prologue: B0 A0 B1 A1 (16 loads); vmcnt(8) -> B0,A0 complete
  issueB(0, 0); issueB(0, 1); issueA(0, 0); issueA(0, 1);
  issueB(1, 0); issueB(1, 1); issueA(1, 0); issueA(1, 1);
  VMCNT8();
  BAR();

  for (int t = 0; t < NT; t++) {
    int abase = (t & 1) * 32768;
    int bbase = 65536 + (t & 1) * 32768;
    // ---- P1: read A(mh0)+B(nh0)
#pragma unroll
    for (int mm = 0; mm < 4; mm++)
#pragma unroll
      for (int ks = 0; ks < 2; ks++)
        aF[mm][ks] = *(const bf16x8*)(ldsc + abase + (wm * 128 + mm * 16 + fr) * 128 +
                                      ((ks * 64 + kk16) ^ xr));
#pragma unroll
    for (int nn = 0; nn < 2; nn++)
#pragma unroll
      for (int ks = 0; ks < 2; ks++)
        bF0[nn][ks] = *(const bf16x8*)(ldsc + bbase + (wn * 64 + nn * 16 + fr) * 128 +
                                       ((ks * 64 + kk16) ^ xr));
    BAR();
    __builtin_amdgcn_s_setprio(1);
#pragma unroll
    for (int mm = 0; mm < 4; mm++)
#pragma unroll
      for (int nn = 0; nn < 2; nn++)
#pragma unroll
        for (int ks = 0; ks < 2; ks++)
          acc[mm][nn] = __builtin_amdgcn_mfma_f32_16x16x32_bf16(aF[mm][ks], bF0[nn][ks], acc[mm][nn], 0, 0, 0);
    __builtin_amdgcn_s_setprio(0);
    BAR();
    // ---- P2: read B(nh1)
#pragma unroll
    for (int nn = 0; nn < 2; nn++)
#pragma unroll
      for (int ks = 0; ks < 2; ks++)
        bF1[nn][ks] = *(const bf16x8*)(ldsc + bbase + (wn * 64 + 32 + nn * 16 + fr) * 128 +
                                       ((ks * 64 + kk16) ^ xr));
    BAR();
    __builtin_amdgcn_s_setprio(1);
#pragma unroll
    for (int mm = 0; mm < 4; mm++)
#pragma unroll
      for (int nn = 0; nn < 2; nn++)
#pragma unroll
        for (int ks = 0; ks < 2; ks++)
          acc[mm][2 + nn] = __builtin_amdgcn_mfma_f32_16x16x32_bf16(aF[mm][ks], bF1[nn][ks], acc[mm][2 + nn], 0, 0, 0);
    __builtin_amdgcn_s_setprio(0);
    BAR();
    // ---- P3: read A(mh1); issue B(t+2)
#pragma unroll
    for (int mm = 0; mm < 4; mm++)
#pragma unroll
      for (int ks = 0; ks < 2; ks++)
        aF[mm][ks] = *(const bf16x8*)(ldsc + abase + (wm * 128 + 64 + mm * 16 + fr) * 128 +
                                      ((ks * 64 + kk16) ^ xr));
    if (t + 2 < NT) { issueB(t + 2, 0); issueB(t + 2, 1); }
    BAR();
    __builtin_amdgcn_s_setprio(1);
#pragma unroll
    for (int mm = 0; mm < 4; mm++)
#pragma unroll
      for (int nn = 0; nn < 2; nn++)
#pragma unroll
        for (int ks = 0; ks < 2; ks++)
          acc[4 + mm][nn] = __builtin_amdgcn_mfma_f32_16x16x32_bf16(aF[mm][ks], bF0[nn][ks], acc[4 + mm][nn], 0, 0, 0);
    __builtin_amdgcn_s_setprio(0);
    BAR();
    // ---- P4: issue A(t+2); counted wait steady / drain at tail
    if (t + 2 < NT) {
      issueA(t + 2, 0); issueA(t + 2, 1);
      VMCNT8();
    } else {
      VMCNT0();
    }
    BAR();
    __builtin_amdgcn_s_setprio(1);
#pragma unroll
    for (int mm = 0; mm < 4; mm++)
#pragma unroll
      for (int nn = 0; nn < 2; nn++)
#pragma unroll
        for (int ks = 0; ks < 2; ks++)
          acc[4 + mm][2 + nn] = __builtin_amdgcn_mfma_f32_16x16x32_bf16(aF[mm][ks], bF1[nn][ks], acc[4 + mm][2 + nn], 0, 0, 0);
    __builtin_amdgcn_s_setprio(0);
    BAR();
  }

  // ---- epilogue
  float biasN[4];
  int cN[4];
#pragma unroll
  for (int n = 0; n < 4; n++) {
    cN[n] = col0 + wn * 64 + (n >> 1) * 32 + (n & 1) * 16 + fr;
    biasN[n] = (EPI == 2) ? 0.f : bias[e * Ncols + cN[n]];
  }
  if constexpr (EPI == 0) {
#pragma unroll
    for (int m = 0; m < 8; m++) {
      int rb = rt * 256 + wm * 128 + (m >> 2) * 64 + (m & 3) * 16 + hi * 4;
#pragma unroll
      for (int j = 0; j < 4; j++) {
        int r = rb + j;
        if (r < cnt) {
#pragma unroll
          for (int n = 0; n < 4; n++) {
            float v = acc[m][n][j] + biasN[n];
            OutBf[(size_t)(off + r) * Ncols + cN[n]] = f2bf(fmaxf(v, 0.f));
          }
        }
      }
    }
  } else if constexpr (EPI == 1) {
#pragma unroll
    for (int m = 0; m < 8; m++) {
      int rb = rt * 256 + wm * 128 + (m >> 2) * 64 + (m & 3) * 16 + hi * 4;
#pragma unroll
      for (int j = 0; j < 4; j++) {
        int r = rb + j;
        if (r < cnt) {
          int idx = off + r;
          int tok = tok_list[idx];
          float g = gate_list[idx];
          size_t erow = ((size_t)e * TKN + tok) * DD;
#pragma unroll
          for (int n = 0; n < 4; n++)
            outF[erow + cN[n]] = (acc[m][n][j] + biasN[n]) * g;
        }
      }
    }
  } else {
    // bf16 K-partial: outP[kq][asg][DD]
#pragma unroll
    for (int m = 0; m < 8; m++) {
      int rb = rt * 256 + wm * 128 + (m >> 2) * 64 + (m & 3) * 16 + hi * 4;
#pragma unroll
      for (int j = 0; j < 4; j++) {
        int r = rb + j;
        if (r < cnt) {
          size_t prow = ((size_t)kq * NASG + off + r) * DD;
#pragma unroll
          for (int n = 0; n < 4; n++)
            outP[prow + cN[n]] = f2bf(acc[m][n][j]);
        }
      }
    }
  }
}

extern "C" void kernel_launch(void* const* d_in, const int* in_sizes, int n_in,
                              void* d_out, int out_size, void* d_ws, size_t ws_size,
                              hipStream_t stream) {
  const float* x     = (const float*)d_in[0];
  const float* noise = (const float*)d_in[1];
  const float* Wg    = (const float*)d_in[2];
  const float* bg    = (const float*)d_in[3];
  const float* Wn    = (const float*)d_in[4];
  const float* bn    = (const float*)d_in[5];
  const float* W1    = (const float*)d_in[6];
  const float* b1    = (const float*)d_in[7];
  const float* W2    = (const float*)d_in[8];
  const float* b2    = (const float*)d_in[9];

  float* final_out  = (float*)d_out;
  float* expert_out = final_out + (size_t)TKN * DD;
  float* gating     = expert_out + (size_t)EE * TKN * DD;

  char* ws = (char*)d_ws;
  size_t o = 0;
  auto alloc = [&](size_t bytes) {
    char* p = ws + o;
    o += bytes;
    o = (o + 255) & ~(size_t)255;
    return p;
  };
  u16*   xb        = (u16*)alloc((size_t)TKN * DD * 2);
  u16*   w1t       = (u16*)alloc((size_t)EE * HH * DD * 2);        // [E][H][D]
  u16*   w2t       = (u16*)alloc((size_t)EE * DD * HH * 2);        // [E][D][H]
  u16*   hbuf      = (u16*)alloc(((size_t)NASG + 256) * HH * 2);   // +256 pad rows
  int*   tok_list  = (int*)alloc((size_t)NASG * 4);
  float* gate_list = (float*)alloc((size_t)NASG * 4);
  int*   sel_e     = (int*)alloc((size_t)NASG * 4);
  float* sel_g     = (float*)alloc((size_t)NASG * 4);
  int*   asg_of    = (int*)alloc((size_t)NASG * 4);
  int*   counts    = (int*)alloc(256);
  int*   offsets   = (int*)alloc(256);
  int*   cursors   = (int*)alloc(256);
  int*   slots     = (int*)alloc(NSLOT * 4);
  u16*   part      = (u16*)alloc((size_t)4 * NASG * DD * 2);       // 134 MB (last)
  bool use_split = (o <= ws_size);

  // zero only gating (router writes just the top-2 entries per token)
  hipMemsetAsync(gating, 0, (size_t)TKN * EE * sizeof(float), stream);

  router_kernel<<<TKN, 256, 0, stream>>>(x, noise, Wg, bg, Wn, bn, gating, xb, sel_e, sel_g);
  hist_scan_kernel<<<1, 256, 0, stream>>>(sel_e, counts, offsets, cursors, slots);
  build_lists_kernel<<<TKN / 256, 256, 0, stream>>>(sel_e, sel_g, cursors, tok_list,
                                                    gate_list, asg_of);
  // zero only the non-selected expert_out rows (gate==0 <=> not selected)
  zerofill_kernel<<<EE * TKN, 256, 0, stream>>>(gating, expert_out);

  transpose_cvt_kernel<<<dim3(HH / 32, DD / 64, EE), dim3(32, 8), 0, stream>>>(W1, w1t, DD, HH);
  transpose_cvt_kernel<<<dim3(DD / 32, HH / 64, EE), dim3(32, 8), 0, stream>>>(W2, w2t, HH, DD);

  // GEMM1: h = relu(x[tok] @ W1[e] + b1), K=1024, N=4096; 16 col-tiles
  gemm8_kernel<DD, DD, true, 0, 4><<<8 * 9 * 16, 512, 0, stream>>>(
      xb, w1t, b1, tok_list, nullptr, counts, offsets, slots, HH, hbuf, nullptr, nullptr);

  if (use_split) {
    // GEMM2 split-K x4: bf16 partials, then merge(+bias,gate)+combine per token
    gemm8_kernel<HH / 4, HH, false, 2, 2><<<8 * 9 * 4 * 4, 512, 0, stream>>>(
        hbuf, w2t, b2, tok_list, gate_list, counts, offsets, slots, DD, nullptr, nullptr, part);
    merge_combine_kernel<<<TKN, 256, 0, stream>>>(part, asg_of, sel_e, sel_g, b2,
                                                  expert_out, final_out);
  } else {
    // fallback: single-shot GEMM2 + combine
    gemm8_kernel<HH, HH, false, 1, 2><<<8 * 9 * 4, 512, 0, stream>>>(
        hbuf, w2t, b2, tok_list, gate_list, counts, offsets, slots, DD, nullptr, expert_out, nullptr);
    combine_kernel<<<TKN, 256, 0, stream>>>(expert_out, sel_e, final_out);
  }
}

// Round 9
// 611.071 us; speedup vs baseline: 4.2851x; 1.0300x over previous
//
#include <hip/hip_runtime.h>
#include <hip/hip_bf16.h>
#include <stdint.h>

// Problem constants: B=8,S=1024,D=1024,E=8,H=4096,top_k=2
#define TKN   8192
#define DD    1024
#define EE    8
#define HH    4096
#define TOPK  2
#define NASG  (TKN * TOPK)      // 16384 assignments
#define NSLOT 72                // >= sum_e ceil(cnt_e/256) (<= 64+7)

typedef unsigned short u16;
typedef __bf16 bf16x8 __attribute__((ext_vector_type(8)));
typedef float  f32x4  __attribute__((ext_vector_type(4)));

__device__ __forceinline__ u16 f2bf(float f) {
  __hip_bfloat16 h = __float2bfloat16(f);
  return __builtin_bit_cast(u16, h);
}
__device__ __forceinline__ float bf2f(u16 u) {
  uint32_t v = ((uint32_t)u) << 16;
  return __builtin_bit_cast(float, v);
}

__device__ __forceinline__ void glds16(const void* g, void* l) {
  __builtin_amdgcn_global_load_lds(
      (__attribute__((address_space(1))) void*)g,
      (__attribute__((address_space(3))) void*)l, 16, 0, 0);
}

#define FENCE() asm volatile("" ::: "memory")
#define BAR()   do { FENCE(); __builtin_amdgcn_s_barrier(); FENCE(); } while (0)
#define VMCNT0() asm volatile("s_waitcnt vmcnt(0)" ::: "memory")

// ---------------- transpose + f32->bf16: [E][R][C] f32 -> [E][C][R] bf16
__global__ __launch_bounds__(256) void transpose_cvt_kernel(
    const float* __restrict__ src, u16* __restrict__ dst, int R, int C) {
  __shared__ float tile[64][33];
  int e = blockIdx.z;
  int c0 = blockIdx.x * 32, r0 = blockIdx.y * 64;
  int tx = threadIdx.x, ty = threadIdx.y;  // 32 x 8
  const float* s = src + (size_t)e * R * C;
  uint32_t* d32 = (uint32_t*)(dst + (size_t)e * R * C);
#pragma unroll
  for (int j = 0; j < 8; j++)
    tile[ty * 8 + j][tx] = s[(size_t)(r0 + ty * 8 + j) * C + c0 + tx];
  __syncthreads();
#pragma unroll
  for (int jj = 0; jj < 4; jj++) {
    int c = c0 + ty * 4 + jj;
    uint32_t lo = f2bf(tile[2 * tx][ty * 4 + jj]);
    uint32_t hi = f2bf(tile[2 * tx + 1][ty * 4 + jj]);
    d32[((size_t)c * R + r0) / 2 + tx] = lo | (hi << 16);
  }
}

// ---------------- router
__global__ __launch_bounds__(256) void router_kernel(
    const float* __restrict__ x, const float* __restrict__ noise,
    const float* __restrict__ Wg, const float* __restrict__ bg,
    const float* __restrict__ Wn, const float* __restrict__ bn,
    float* __restrict__ gating, u16* __restrict__ xb,
    int* __restrict__ sel_e, float* __restrict__ sel_g) {
  int t = blockIdx.x;
  int tid = threadIdx.x;
  float acc[16];
#pragma unroll
  for (int j = 0; j < 16; j++) acc[j] = 0.f;
  for (int i = tid; i < DD; i += 256) {
    float xv = x[(size_t)t * DD + i];
    xb[(size_t)t * DD + i] = f2bf(xv);
    const float4* g4 = (const float4*)(Wg + (size_t)i * EE);
    const float4* n4 = (const float4*)(Wn + (size_t)i * EE);
    float4 ga = g4[0], gb = g4[1];
    float4 na = n4[0], nb = n4[1];
    acc[0] += xv * ga.x;  acc[1] += xv * ga.y;  acc[2] += xv * ga.z;  acc[3] += xv * ga.w;
    acc[4] += xv * gb.x;  acc[5] += xv * gb.y;  acc[6] += xv * gb.z;  acc[7] += xv * gb.w;
    acc[8] += xv * na.x;  acc[9] += xv * na.y;  acc[10] += xv * na.z; acc[11] += xv * na.w;
    acc[12] += xv * nb.x; acc[13] += xv * nb.y; acc[14] += xv * nb.z; acc[15] += xv * nb.w;
  }
  __shared__ float red[4][16];
  int lane = tid & 63, wv = tid >> 6;
#pragma unroll
  for (int j = 0; j < 16; j++) {
    float v = acc[j];
    for (int o = 32; o > 0; o >>= 1) v += __shfl_down(v, o);
    acc[j] = v;
  }
  if (lane == 0) {
#pragma unroll
    for (int j = 0; j < 16; j++) red[wv][j] = acc[j];
  }
  __syncthreads();
  if (tid == 0) {
    float nz[EE];
#pragma unroll
    for (int e = 0; e < EE; e++) {
      float dg = red[0][e] + red[1][e] + red[2][e] + red[3][e] + bg[e];
      float dn = red[0][8 + e] + red[1][8 + e] + red[2][8 + e] + red[3][8 + e] + bn[e];
      float sp = fmaxf(dn, 0.f) + log1pf(expf(-fabsf(dn)));
      nz[e] = dg + noise[(size_t)t * EE + e] * sp;
    }
    int m1 = 0;
    for (int e = 1; e < EE; e++) if (nz[e] > nz[m1]) m1 = e;
    int m2 = (m1 == 0) ? 1 : 0;
    for (int e = 0; e < EE; e++) if (e != m1 && nz[e] > nz[m2]) m2 = e;
    float eb = expf(nz[m2] - nz[m1]);
    float den = 1.f + eb;
    float g1 = 1.f / den, g2 = eb / den;
    gating[(size_t)t * EE + m1] = g1;
    gating[(size_t)t * EE + m2] = g2;
    sel_e[t * 2] = m1; sel_e[t * 2 + 1] = m2;
    sel_g[t * 2] = g1; sel_g[t * 2 + 1] = g2;
  }
}

// ---------------- histogram + scan + slot table (1 block)
__global__ __launch_bounds__(256) void hist_scan_kernel(
    const int* __restrict__ sel_e, int* __restrict__ counts,
    int* __restrict__ offsets, int* __restrict__ cursors,
    int* __restrict__ slots) {
  __shared__ int hist[EE];
  int tid = threadIdx.x;
  if (tid < EE) hist[tid] = 0;
  __syncthreads();
  for (int i = tid; i < NASG; i += 256) atomicAdd(&hist[sel_e[i]], 1);
  __syncthreads();
  if (tid == 0) {
    int off = 0, ns = 0;
    for (int e = 0; e < EE; e++) {
      int c = hist[e];
      counts[e] = c; offsets[e] = off; cursors[e] = off; off += c;
      int nrt = (c + 255) >> 8;
      for (int rt = 0; rt < nrt; rt++) slots[ns++] = (e << 16) | rt;
    }
    for (; ns < NSLOT; ns++) slots[ns] = -1;
  }
}

// ---------------- build per-expert token lists (+ token->assignment-slot map)
__global__ __launch_bounds__(256) void build_lists_kernel(
    const int* __restrict__ sel_e, const float* __restrict__ sel_g,
    int* __restrict__ cursors, int* __restrict__ tok_list,
    float* __restrict__ gate_list, int* __restrict__ asg_of) {
  int t = blockIdx.x * 256 + threadIdx.x;
  int lane = threadIdx.x & 63;
#pragma unroll
  for (int k = 0; k < TOPK; k++) {
    int e = sel_e[t * 2 + k];
    float g = sel_g[t * 2 + k];
    for (int ee = 0; ee < EE; ee++) {
      unsigned long long m = __ballot(e == ee);
      if (m) {
        int leader = __ffsll(m) - 1;
        int base = 0;
        if (lane == leader) base = atomicAdd(&cursors[ee], __popcll(m));
        base = __shfl(base, leader);
        if (e == ee) {
          int slot = base + __popcll(m & ((1ull << lane) - 1ull));
          tok_list[slot] = t;
          gate_list[slot] = g;
          asg_of[t * 2 + k] = slot;
        }
      }
    }
  }
}

// ---------------- zero-fill non-selected expert_out rows (gate == 0 exactly)
__global__ __launch_bounds__(256) void zerofill_kernel(
    const float* __restrict__ gating, float* __restrict__ expert_out) {
  int id = blockIdx.x;              // 0 .. EE*TKN-1
  int e = id >> 13, t = id & (TKN - 1);
  if (gating[(size_t)t * EE + e] != 0.f) return;
  float4* p = (float4*)(expert_out + ((size_t)e * TKN + t) * DD);
  p[threadIdx.x] = (float4){0.f, 0.f, 0.f, 0.f};
}

// ---------------- combine (fallback path): final = expert rows sum
__global__ __launch_bounds__(256) void combine_kernel(
    const float* __restrict__ expert_out, const int* __restrict__ sel_e,
    float* __restrict__ final_out) {
  int t = blockIdx.x;
  int e1 = sel_e[2 * t], e2 = sel_e[2 * t + 1];
  const float4* r1 = (const float4*)(expert_out + ((size_t)e1 * TKN + t) * DD);
  const float4* r2 = (const float4*)(expert_out + ((size_t)e2 * TKN + t) * DD);
  float4* o = (float4*)(final_out + (size_t)t * DD);
  int i = threadIdx.x;
  float4 a = r1[i], b = r2[i];
  o[i] = (float4){a.x + b.x, a.y + b.y, a.z + b.z, a.w + b.w};
}

// ---------------- merge 4 bf16 K-partials + bias + gate -> expert rows + final
__global__ __launch_bounds__(256) void merge_combine_kernel(
    const u16* __restrict__ part, const int* __restrict__ asg_of,
    const int* __restrict__ sel_e, const float* __restrict__ sel_g,
    const float* __restrict__ b2, float* __restrict__ expert_out,
    float* __restrict__ final_out) {
  int t = blockIdx.x;
  int i = threadIdx.x;
  int i1 = asg_of[2 * t], i2 = asg_of[2 * t + 1];
  int e1 = sel_e[2 * t], e2 = sel_e[2 * t + 1];
  float g1 = sel_g[2 * t], g2 = sel_g[2 * t + 1];
  float s1[4] = {0.f, 0.f, 0.f, 0.f}, s2[4] = {0.f, 0.f, 0.f, 0.f};
#pragma unroll
  for (int kq = 0; kq < 4; kq++) {
    ushort4 a = ((const ushort4*)(part + ((size_t)kq * NASG + i1) * DD))[i];
    ushort4 b = ((const ushort4*)(part + ((size_t)kq * NASG + i2) * DD))[i];
    s1[0] += bf2f(a.x); s1[1] += bf2f(a.y); s1[2] += bf2f(a.z); s1[3] += bf2f(a.w);
    s2[0] += bf2f(b.x); s2[1] += bf2f(b.y); s2[2] += bf2f(b.z); s2[3] += bf2f(b.w);
  }
  float4 bb1 = ((const float4*)(b2 + (size_t)e1 * DD))[i];
  float4 bb2 = ((const float4*)(b2 + (size_t)e2 * DD))[i];
  float4 y1 = {(s1[0] + bb1.x) * g1, (s1[1] + bb1.y) * g1,
               (s1[2] + bb1.z) * g1, (s1[3] + bb1.w) * g1};
  float4 y2 = {(s2[0] + bb2.x) * g2, (s2[1] + bb2.y) * g2,
               (s2[2] + bb2.z) * g2, (s2[3] + bb2.w) * g2};
  ((float4*)(expert_out + ((size_t)e1 * TKN + t) * DD))[i] = y1;
  ((float4*)(expert_out + ((size_t)e2 * TKN + t) * DD))[i] = y2;
  ((float4*)(final_out + (size_t)t * DD))[i] =
      (float4){y1.x + y2.x, y1.y + y2.y, y1.z + y2.z, y1.w + y2.w};
}

// ---------------- 256x256 / BK=64 / 8-wave grouped GEMM, 1-barrier-per-tile
// Per K-tile: { issue glds(t+1) [depth-1 prefetch, parity (t+1)&1];
//   read A-lo+B frags; MFMA x32; read A-hi; MFMA x32; vmcnt(0); barrier }.
// No intra-tile barriers: with 2 waves/SIMD free-running inside the tile the
// LDS pipe (2300 cyc of ds_read) overlaps the MFMA pipe (2483 cyc) instead of
// adding (the round-8 4-phase lockstep cost ~6000 cyc/tile).
// WAR ledger: glds(t+1) writes parity (t+1)&1; its last readers were R(t-1),
// drained per-wave (compiler lgkmcnt before MFMA(t-1)) before the tile-(t-1)
// barrier. RAW: R(t) gated by every wave's vmcnt(0) [drains own glds(t)] +
// barrier at end of tile t-1. Full drain each tile -> no counted-vmcnt races.
// EPI: 0 = relu->bf16 OutBf; 1 = (acc+bias)*gate -> f32 outF; 2 = bf16
// K-partial -> outP[kq][asg][DD].
// Decode (1-D grid, kq-outer within XCD): gid -> xcd=gid&7, q=gid>>3,
// kq=q/(9<<LOGC), r=q%(9<<LOGC), slot=xcd*9+(r>>LOGC), ct=r&mask.
// LDS swizzle: stored 16B chunk c of row r holds global chunk c^(r&7) —
// linear glds dest + inverse-swizzled per-lane global source (involution).
template<int KLOOP, int KSTRIDE, bool GATHER, int EPI, int LOGC>
__global__ __launch_bounds__(512, 2) void gemm8_kernel(
    const u16* __restrict__ A, const u16* __restrict__ Bm,
    const float* __restrict__ bias, const int* __restrict__ tok_list,
    const float* __restrict__ gate_list, const int* __restrict__ counts,
    const int* __restrict__ offsets, const int* __restrict__ slots,
    int Ncols, u16* __restrict__ OutBf, float* __restrict__ outF,
    u16* __restrict__ outP) {
  constexpr int NT = KLOOP / 64;
  int gid = blockIdx.x;
  int q = gid >> 3;
  constexpr int PERX = 9 << LOGC;
  int kq = q / PERX;
  int r0q = q - kq * PERX;
  int slot = (gid & 7) * 9 + (r0q >> LOGC);
  int ct = r0q & ((1 << LOGC) - 1);
  int packed = slots[slot];
  if (packed < 0) return;
  int e = packed >> 16;
  int rt = packed & 0xffff;
  int cnt = counts[e];
  int off = offsets[e];
  int col0 = ct * 256;
  int k0e = kq * KLOOP;   // element offset of this K-slice

  __shared__ __attribute__((aligned(16))) char ldsc[131072];  // A 64K | B 64K

  int tid = threadIdx.x;
  int w = tid >> 6, l = tid & 63;
  int wm = w >> 2, wn = w & 3;            // 2 x 4 wave grid
  int fr = l & 15, hi = l >> 4;
  int kk16 = hi << 4;
  int xr = (fr & 7) << 4;

  int rl0 = w * 8 + (l >> 3);
  int slotE = ((l & 7) ^ ((l >> 3) & 7)) << 3;  // pre-swizzled 8-elem slot
  const u16* aptr[4];
  const u16* bptr[4];
#pragma unroll
  for (int i = 0; i < 4; i++) {
    int r = rt * 256 + rl0 + i * 64;
    if (GATHER) {
      int idx = min(off + r, NASG - 1);
      aptr[i] = A + (size_t)tok_list[idx] * KSTRIDE + k0e + slotE;
    } else {
      aptr[i] = A + (size_t)(off + r) * KSTRIDE + k0e + slotE;
    }
    bptr[i] = Bm + ((size_t)e * Ncols + col0 + rl0 + i * 64) * KSTRIDE + k0e + slotE;
  }
  char* ldsA = ldsc;
  char* ldsB = ldsc + 65536;

  auto issueAB = [&](int t) {
    char* db = ldsB + (t & 1) * 32768 + w * 1024;
    char* da = ldsA + (t & 1) * 32768 + w * 1024;
    glds16(bptr[0] + t * 64, db);
    glds16(bptr[1] + t * 64, db + 8192);
    glds16(bptr[2] + t * 64, db + 16384);
    glds16(bptr[3] + t * 64, db + 24576);
    glds16(aptr[0] + t * 64, da);
    glds16(aptr[1] + t * 64, da + 8192);
    glds16(aptr[2] + t * 64, da + 16384);
    glds16(aptr[3] + t * 64, da + 24576);
  };

  f32x4 acc[8][4];
#pragma unroll
  for (int m = 0; m < 8; m++)
#pragma unroll
    for (int n = 0; n < 4; n++) acc[m][n] = (f32x4){0.f, 0.f, 0.f, 0.f};
  bf16x8 aF[4][2], bF0[2][2], bF1[2][2];

  // prologue: stage tile 0; drain; barrier
  issueAB(0);
  VMCNT0();
  BAR();

  for (int t = 0; t < NT; t++) {
    int abase = (t & 1) * 32768;
    int bbase = 65536 + (t & 1) * 32768;
    // depth-1 prefetch into parity (t+1)&1 (its last readers R(t-1) drained)
    if (t + 1 < NT) issueAB(t + 1);
    // read A-lo + all B fragments
#pragma unroll
    for (int mm = 0; mm < 4; mm++)
#pragma unroll
      for (int ks = 0; ks < 2; ks++)
        aF[mm][ks] = *(const bf16x8*)(ldsc + abase + (wm * 128 + mm * 16 + fr) * 128 +
                                      ((ks * 64 + kk16) ^ xr));
#pragma unroll
    for (int nn = 0; nn < 2; nn++)
#pragma unroll
      for (int ks = 0; ks < 2; ks++) {
        bF0[nn][ks] = *(const bf16x8*)(ldsc + bbase + (wn * 64 + nn * 16 + fr) * 128 +
                                       ((ks * 64 + kk16) ^ xr));
        bF1[nn][ks] = *(const bf16x8*)(ldsc + bbase + (wn * 64 + 32 + nn * 16 + fr) * 128 +
                                       ((ks * 64 + kk16) ^ xr));
      }
    __builtin_amdgcn_s_setprio(1);
#pragma unroll
    for (int mm = 0; mm < 4; mm++)
#pragma unroll
      for (int nn = 0; nn < 2; nn++)
#pragma unroll
        for (int ks = 0; ks < 2; ks++) {
          acc[mm][nn]     = __builtin_amdgcn_mfma_f32_16x16x32_bf16(aF[mm][ks], bF0[nn][ks], acc[mm][nn], 0, 0, 0);
          acc[mm][2 + nn] = __builtin_amdgcn_mfma_f32_16x16x32_bf16(aF[mm][ks], bF1[nn][ks], acc[mm][2 + nn], 0, 0, 0);
        }
    __builtin_amdgcn_s_setprio(0);
    // read A-hi (reuses aF; WAR on regs handled by compiler)
#pragma unroll
    for (int mm = 0; mm < 4; mm++)
#pragma unroll
      for (int ks = 0; ks < 2; ks++)
        aF[mm][ks] = *(const bf16x8*)(ldsc + abase + (wm * 128 + 64 + mm * 16 + fr) * 128 +
                                      ((ks * 64 + kk16) ^ xr));
    __builtin_amdgcn_s_setprio(1);
#pragma unroll
    for (int mm = 0; mm < 4; mm++)
#pragma unroll
      for (int nn = 0; nn < 2; nn++)
#pragma unroll
        for (int ks = 0; ks < 2; ks++) {
          acc[4 + mm][nn]     = __builtin_amdgcn_mfma_f32_16x16x32_bf16(aF[mm][ks], bF0[nn][ks], acc[4 + mm][nn], 0, 0, 0);
          acc[4 + mm][2 + nn] = __builtin_amdgcn_mfma_f32_16x16x32_bf16(aF[mm][ks], bF1[nn][ks], acc[4 + mm][2 + nn], 0, 0, 0);
        }
    __builtin_amdgcn_s_setprio(0);
    // drain own glds(t+1) (issued ~2500 cyc ago -> ~no stall) and sync
    VMCNT0();
    BAR();
  }

  // ---- epilogue
  float biasN[4];
  int cN[4];
#pragma unroll
  for (int n = 0; n < 4; n++) {
    cN[n] = col0 + wn * 64 + (n >> 1) * 32 + (n & 1) * 16 + fr;
    biasN[n] = (EPI == 2) ? 0.f : bias[e * Ncols + cN[n]];
  }
  if constexpr (EPI == 0) {
#pragma unroll
    for (int m = 0; m < 8; m++) {
      int rb = rt * 256 + wm * 128 + (m >> 2) * 64 + (m & 3) * 16 + hi * 4;
#pragma unroll
      for (int j = 0; j < 4; j++) {
        int r = rb + j;
        if (r < cnt) {
#pragma unroll
          for (int n = 0; n < 4; n++) {
            float v = acc[m][n][j] + biasN[n];
            OutBf[(size_t)(off + r) * Ncols + cN[n]] = f2bf(fmaxf(v, 0.f));
          }
        }
      }
    }
  } else if constexpr (EPI == 1) {
#pragma unroll
    for (int m = 0; m < 8; m++) {
      int rb = rt * 256 + wm * 128 + (m >> 2) * 64 + (m & 3) * 16 + hi * 4;
#pragma unroll
      for (int j = 0; j < 4; j++) {
        int r = rb + j;
        if (r < cnt) {
          int idx = off + r;
          int tok = tok_list[idx];
          float g = gate_list[idx];
          size_t erow = ((size_t)e * TKN + tok) * DD;
#pragma unroll
          for (int n = 0; n < 4; n++)
            outF[erow + cN[n]] = (acc[m][n][j] + biasN[n]) * g;
        }
      }
    }
  } else {
    // bf16 K-partial: outP[kq][asg][DD]
#pragma unroll
    for (int m = 0; m < 8; m++) {
      int rb = rt * 256 + wm * 128 + (m >> 2) * 64 + (m & 3) * 16 + hi * 4;
#pragma unroll
      for (int j = 0; j < 4; j++) {
        int r = rb + j;
        if (r < cnt) {
          size_t prow = ((size_t)kq * NASG + off + r) * DD;
#pragma unroll
          for (int n = 0; n < 4; n++)
            outP[prow + cN[n]] = f2bf(acc[m][n][j]);
        }
      }
    }
  }
}

extern "C" void kernel_launch(void* const* d_in, const int* in_sizes, int n_in,
                              void* d_out, int out_size, void* d_ws, size_t ws_size,
                              hipStream_t stream) {
  const float* x     = (const float*)d_in[0];
  const float* noise = (const float*)d_in[1];
  const float* Wg    = (const float*)d_in[2];
  const float* bg    = (const float*)d_in[3];
  const float* Wn    = (const float*)d_in[4];
  const float* bn    = (const float*)d_in[5];
  const float* W1    = (const float*)d_in[6];
  const float* b1    = (const float*)d_in[7];
  const float* W2    = (const float*)d_in[8];
  const float* b2    = (const float*)d_in[9];

  float* final_out  = (float*)d_out;
  float* expert_out = final_out + (size_t)TKN * DD;
  float* gating     = expert_out + (size_t)EE * TKN * DD;

  char* ws = (char*)d_ws;
  size_t o = 0;
  auto alloc = [&](size_t bytes) {
    char* p = ws + o;
    o += bytes;
    o = (o + 255) & ~(size_t)255;
    return p;
  };
  u16*   xb        = (u16*)alloc((size_t)TKN * DD * 2);
  u16*   w1t       = (u16*)alloc((size_t)EE * HH * DD * 2);        // [E][H][D]
  u16*   w2t       = (u16*)alloc((size_t)EE * DD * HH * 2);        // [E][D][H]
  u16*   hbuf      = (u16*)alloc(((size_t)NASG + 256) * HH * 2);   // +256 pad rows
  int*   tok_list  = (int*)alloc((size_t)NASG * 4);
  float* gate_list = (float*)alloc((size_t)NASG * 4);
  int*   sel_e     = (int*)alloc((size_t)NASG * 4);
  float* sel_g     = (float*)alloc((size_t)NASG * 4);
  int*   asg_of    = (int*)alloc((size_t)NASG * 4);
  int*   counts    = (int*)alloc(256);
  int*   offsets   = (int*)alloc(256);
  int*   cursors   = (int*)alloc(256);
  int*   slots     = (int*)alloc(NSLOT * 4);
  u16*   part      = (u16*)alloc((size_t)4 * NASG * DD * 2);       // 134 MB (last)
  bool use_split = (o <= ws_size);

  // zero only gating (router writes just the top-2 entries per token)
  hipMemsetAsync(gating, 0, (size_t)TKN * EE * sizeof(float), stream);

  router_kernel<<<TKN, 256, 0, stream>>>(x, noise, Wg, bg, Wn, bn, gating, xb, sel_e, sel_g);
  hist_scan_kernel<<<1, 256, 0, stream>>>(sel_e, counts, offsets, cursors, slots);
  build_lists_kernel<<<TKN / 256, 256, 0, stream>>>(sel_e, sel_g, cursors, tok_list,
                                                    gate_list, asg_of);
  // zero only the non-selected expert_out rows (gate==0 <=> not selected)
  zerofill_kernel<<<EE * TKN, 256, 0, stream>>>(gating, expert_out);

  transpose_cvt_kernel<<<dim3(HH / 32, DD / 64, EE), dim3(32, 8), 0, stream>>>(W1, w1t, DD, HH);
  transpose_cvt_kernel<<<dim3(DD / 32, HH / 64, EE), dim3(32, 8), 0, stream>>>(W2, w2t, HH, DD);

  // GEMM1: h = relu(x[tok] @ W1[e] + b1), K=1024, N=4096; 16 col-tiles
  gemm8_kernel<DD, DD, true, 0, 4><<<8 * 9 * 16, 512, 0, stream>>>(
      xb, w1t, b1, tok_list, nullptr, counts, offsets, slots, HH, hbuf, nullptr, nullptr);

  if (use_split) {
    // GEMM2 split-K x4: bf16 partials, then merge(+bias,gate)+combine per token
    gemm8_kernel<HH / 4, HH, false, 2, 2><<<8 * 9 * 4 * 4, 512, 0, stream>>>(
        hbuf, w2t, b2, tok_list, gate_list, counts, offsets, slots, DD, nullptr, nullptr, part);
    merge_combine_kernel<<<TKN, 256, 0, stream>>>(part, asg_of, sel_e, sel_g, b2,
                                                  expert_out, final_out);
  } else {
    // fallback: single-shot GEMM2 + combine
    gemm8_kernel<HH, HH, false, 1, 2><<<8 * 9 * 4, 512, 0, stream>>>(
        hbuf, w2t, b2, tok_list, gate_list, counts, offsets, slots, DD, nullptr, expert_out, nullptr);
    combine_kernel<<<TKN, 256, 0, stream>>>(expert_out, sel_e, final_out);
  }
}

// Round 10
// 609.669 us; speedup vs baseline: 4.2950x; 1.0023x over previous
//
#include <hip/hip_runtime.h>
#include <hip/hip_bf16.h>
#include <stdint.h>

// Problem constants: B=8,S=1024,D=1024,E=8,H=4096,top_k=2
#define TKN   8192
#define DD    1024
#define EE    8
#define HH    4096
#define TOPK  2
#define NASG  (TKN * TOPK)      // 16384 assignments
#define NSLOT 72                // >= sum_e ceil(cnt_e/256) (<= 64+7)

typedef unsigned short u16;
typedef __bf16 bf16x8 __attribute__((ext_vector_type(8)));
typedef float  f32x4  __attribute__((ext_vector_type(4)));

__device__ __forceinline__ u16 f2bf(float f) {
  __hip_bfloat16 h = __float2bfloat16(f);
  return __builtin_bit_cast(u16, h);
}
__device__ __forceinline__ float bf2f(u16 u) {
  uint32_t v = ((uint32_t)u) << 16;
  return __builtin_bit_cast(float, v);
}

__device__ __forceinline__ void glds16(const void* g, void* l) {
  __builtin_amdgcn_global_load_lds(
      (__attribute__((address_space(1))) void*)g,
      (__attribute__((address_space(3))) void*)l, 16, 0, 0);
}

#define FENCE() asm volatile("" ::: "memory")
#define BAR()   do { FENCE(); __builtin_amdgcn_s_barrier(); FENCE(); } while (0)
#define VMCNT0() asm volatile("s_waitcnt vmcnt(0)" ::: "memory")

// ---------------- transpose + f32->bf16: [E][R][C] f32 -> [E][C][R] bf16
__global__ __launch_bounds__(256) void transpose_cvt_kernel(
    const float* __restrict__ src, u16* __restrict__ dst, int R, int C) {
  __shared__ float tile[64][33];
  int e = blockIdx.z;
  int c0 = blockIdx.x * 32, r0 = blockIdx.y * 64;
  int tx = threadIdx.x, ty = threadIdx.y;  // 32 x 8
  const float* s = src + (size_t)e * R * C;
  uint32_t* d32 = (uint32_t*)(dst + (size_t)e * R * C);
#pragma unroll
  for (int j = 0; j < 8; j++)
    tile[ty * 8 + j][tx] = s[(size_t)(r0 + ty * 8 + j) * C + c0 + tx];
  __syncthreads();
#pragma unroll
  for (int jj = 0; jj < 4; jj++) {
    int c = c0 + ty * 4 + jj;
    uint32_t lo = f2bf(tile[2 * tx][ty * 4 + jj]);
    uint32_t hi = f2bf(tile[2 * tx + 1][ty * 4 + jj]);
    d32[((size_t)c * R + r0) / 2 + tx] = lo | (hi << 16);
  }
}

// ---------------- router
__global__ __launch_bounds__(256) void router_kernel(
    const float* __restrict__ x, const float* __restrict__ noise,
    const float* __restrict__ Wg, const float* __restrict__ bg,
    const float* __restrict__ Wn, const float* __restrict__ bn,
    float* __restrict__ gating, u16* __restrict__ xb,
    int* __restrict__ sel_e, float* __restrict__ sel_g) {
  int t = blockIdx.x;
  int tid = threadIdx.x;
  float acc[16];
#pragma unroll
  for (int j = 0; j < 16; j++) acc[j] = 0.f;
  for (int i = tid; i < DD; i += 256) {
    float xv = x[(size_t)t * DD + i];
    xb[(size_t)t * DD + i] = f2bf(xv);
    const float4* g4 = (const float4*)(Wg + (size_t)i * EE);
    const float4* n4 = (const float4*)(Wn + (size_t)i * EE);
    float4 ga = g4[0], gb = g4[1];
    float4 na = n4[0], nb = n4[1];
    acc[0] += xv * ga.x;  acc[1] += xv * ga.y;  acc[2] += xv * ga.z;  acc[3] += xv * ga.w;
    acc[4] += xv * gb.x;  acc[5] += xv * gb.y;  acc[6] += xv * gb.z;  acc[7] += xv * gb.w;
    acc[8] += xv * na.x;  acc[9] += xv * na.y;  acc[10] += xv * na.z; acc[11] += xv * na.w;
    acc[12] += xv * nb.x; acc[13] += xv * nb.y; acc[14] += xv * nb.z; acc[15] += xv * nb.w;
  }
  __shared__ float red[4][16];
  int lane = tid & 63, wv = tid >> 6;
#pragma unroll
  for (int j = 0; j < 16; j++) {
    float v = acc[j];
    for (int o = 32; o > 0; o >>= 1) v += __shfl_down(v, o);
    acc[j] = v;
  }
  if (lane == 0) {
#pragma unroll
    for (int j = 0; j < 16; j++) red[wv][j] = acc[j];
  }
  __syncthreads();
  if (tid == 0) {
    float nz[EE];
#pragma unroll
    for (int e = 0; e < EE; e++) {
      float dg = red[0][e] + red[1][e] + red[2][e] + red[3][e] + bg[e];
      float dn = red[0][8 + e] + red[1][8 + e] + red[2][8 + e] + red[3][8 + e] + bn[e];
      float sp = fmaxf(dn, 0.f) + log1pf(expf(-fabsf(dn)));
      nz[e] = dg + noise[(size_t)t * EE + e] * sp;
    }
    int m1 = 0;
    for (int e = 1; e < EE; e++) if (nz[e] > nz[m1]) m1 = e;
    int m2 = (m1 == 0) ? 1 : 0;
    for (int e = 0; e < EE; e++) if (e != m1 && nz[e] > nz[m2]) m2 = e;
    float eb = expf(nz[m2] - nz[m1]);
    float den = 1.f + eb;
    float g1 = 1.f / den, g2 = eb / den;
    gating[(size_t)t * EE + m1] = g1;
    gating[(size_t)t * EE + m2] = g2;
    sel_e[t * 2] = m1; sel_e[t * 2 + 1] = m2;
    sel_g[t * 2] = g1; sel_g[t * 2 + 1] = g2;
  }
}

// ---------------- histogram + scan + slot table (1 block)
__global__ __launch_bounds__(256) void hist_scan_kernel(
    const int* __restrict__ sel_e, int* __restrict__ counts,
    int* __restrict__ offsets, int* __restrict__ cursors,
    int* __restrict__ slots) {
  __shared__ int hist[EE];
  int tid = threadIdx.x;
  if (tid < EE) hist[tid] = 0;
  __syncthreads();
  for (int i = tid; i < NASG; i += 256) atomicAdd(&hist[sel_e[i]], 1);
  __syncthreads();
  if (tid == 0) {
    int off = 0, ns = 0;
    for (int e = 0; e < EE; e++) {
      int c = hist[e];
      counts[e] = c; offsets[e] = off; cursors[e] = off; off += c;
      int nrt = (c + 255) >> 8;
      for (int rt = 0; rt < nrt; rt++) slots[ns++] = (e << 16) | rt;
    }
    for (; ns < NSLOT; ns++) slots[ns] = -1;
  }
}

// ---------------- build per-expert token lists (+ token->assignment-slot map)
__global__ __launch_bounds__(256) void build_lists_kernel(
    const int* __restrict__ sel_e, const float* __restrict__ sel_g,
    int* __restrict__ cursors, int* __restrict__ tok_list,
    float* __restrict__ gate_list, int* __restrict__ asg_of) {
  int t = blockIdx.x * 256 + threadIdx.x;
  int lane = threadIdx.x & 63;
#pragma unroll
  for (int k = 0; k < TOPK; k++) {
    int e = sel_e[t * 2 + k];
    float g = sel_g[t * 2 + k];
    for (int ee = 0; ee < EE; ee++) {
      unsigned long long m = __ballot(e == ee);
      if (m) {
        int leader = __ffsll(m) - 1;
        int base = 0;
        if (lane == leader) base = atomicAdd(&cursors[ee], __popcll(m));
        base = __shfl(base, leader);
        if (e == ee) {
          int slot = base + __popcll(m & ((1ull << lane) - 1ull));
          tok_list[slot] = t;
          gate_list[slot] = g;
          asg_of[t * 2 + k] = slot;
        }
      }
    }
  }
}

// ---------------- zero-fill non-selected expert_out rows (gate == 0 exactly)
__global__ __launch_bounds__(256) void zerofill_kernel(
    const float* __restrict__ gating, float* __restrict__ expert_out) {
  int id = blockIdx.x;              // 0 .. EE*TKN-1
  int e = id >> 13, t = id & (TKN - 1);
  if (gating[(size_t)t * EE + e] != 0.f) return;
  float4* p = (float4*)(expert_out + ((size_t)e * TKN + t) * DD);
  p[threadIdx.x] = (float4){0.f, 0.f, 0.f, 0.f};
}

// ---------------- combine (fallback path): final = expert rows sum
__global__ __launch_bounds__(256) void combine_kernel(
    const float* __restrict__ expert_out, const int* __restrict__ sel_e,
    float* __restrict__ final_out) {
  int t = blockIdx.x;
  int e1 = sel_e[2 * t], e2 = sel_e[2 * t + 1];
  const float4* r1 = (const float4*)(expert_out + ((size_t)e1 * TKN + t) * DD);
  const float4* r2 = (const float4*)(expert_out + ((size_t)e2 * TKN + t) * DD);
  float4* o = (float4*)(final_out + (size_t)t * DD);
  int i = threadIdx.x;
  float4 a = r1[i], b = r2[i];
  o[i] = (float4){a.x + b.x, a.y + b.y, a.z + b.z, a.w + b.w};
}

// ---------------- merge 4 bf16 K-partials + bias + gate -> expert rows + final
__global__ __launch_bounds__(256) void merge_combine_kernel(
    const u16* __restrict__ part, const int* __restrict__ asg_of,
    const int* __restrict__ sel_e, const float* __restrict__ sel_g,
    const float* __restrict__ b2, float* __restrict__ expert_out,
    float* __restrict__ final_out) {
  int t = blockIdx.x;
  int i = threadIdx.x;
  int i1 = asg_of[2 * t], i2 = asg_of[2 * t + 1];
  int e1 = sel_e[2 * t], e2 = sel_e[2 * t + 1];
  float g1 = sel_g[2 * t], g2 = sel_g[2 * t + 1];
  float s1[4] = {0.f, 0.f, 0.f, 0.f}, s2[4] = {0.f, 0.f, 0.f, 0.f};
#pragma unroll
  for (int kq = 0; kq < 4; kq++) {
    ushort4 a = ((const ushort4*)(part + ((size_t)kq * NASG + i1) * DD))[i];
    ushort4 b = ((const ushort4*)(part + ((size_t)kq * NASG + i2) * DD))[i];
    s1[0] += bf2f(a.x); s1[1] += bf2f(a.y); s1[2] += bf2f(a.z); s1[3] += bf2f(a.w);
    s2[0] += bf2f(b.x); s2[1] += bf2f(b.y); s2[2] += bf2f(b.z); s2[3] += bf2f(b.w);
  }
  float4 bb1 = ((const float4*)(b2 + (size_t)e1 * DD))[i];
  float4 bb2 = ((const float4*)(b2 + (size_t)e2 * DD))[i];
  float4 y1 = {(s1[0] + bb1.x) * g1, (s1[1] + bb1.y) * g1,
               (s1[2] + bb1.z) * g1, (s1[3] + bb1.w) * g1};
  float4 y2 = {(s2[0] + bb2.x) * g2, (s2[1] + bb2.y) * g2,
               (s2[2] + bb2.z) * g2, (s2[3] + bb2.w) * g2};
  ((float4*)(expert_out + ((size_t)e1 * TKN + t) * DD))[i] = y1;
  ((float4*)(expert_out + ((size_t)e2 * TKN + t) * DD))[i] = y2;
  ((float4*)(final_out + (size_t)t * DD))[i] =
      (float4){y1.x + y2.x, y1.y + y2.y, y1.z + y2.z, y1.w + y2.w};
}

// ---------------- 256x256 / BK=64 / 8-wave grouped GEMM, 1-barrier-per-tile,
// interleaved aHi refill.
// Per K-tile: { issue glds(t+1); read aLo(8) + b(8); for mm=0..3 { 8 MFMA on
// aF[mm] ; sched_barrier ; refill aF[mm] <- aHi row ; sched_barrier } ; 32
// MFMA-hi ; vmcnt(0) ; barrier }.
// Why: round-9 reused aF for lo/hi with the refill AFTER all 32 MFMA-lo —
// in-order issue serialized LDS (2300cyc) + MFMA (2483cyc) per tile (5550
// measured). Refilling per-8-MFMA-group lets the 8 hi-reads run in the LDS
// pipe under the remaining MFMA-lo issues. sched_barrier(0) pins the refill
// in its slot (hoisting above the group would need a 2nd reg set -> >256
// regs/wave -> spill, the round-7 failure; sinking recreates round-9).
// Budget: 256 regs/wave at 512-thread blocks (2 waves/SIMD x 512-reg pool);
// this reorder keeps round-9's liveness (~236).
// WAR/RAW ledger unchanged from round 9 (depth-1 prefetch, full drain/tile).
// EPI: 0 = relu->bf16 OutBf; 1 = (acc+bias)*gate -> f32 outF; 2 = bf16
// K-partial -> outP[kq][asg][DD].
// Decode (1-D grid, kq-outer within XCD): gid -> xcd=gid&7, q=gid>>3,
// kq=q/(9<<LOGC), r=q%(9<<LOGC), slot=xcd*9+(r>>LOGC), ct=r&mask.
// LDS swizzle: stored 16B chunk c of row r holds global chunk c^(r&7) —
// linear glds dest + inverse-swizzled per-lane global source (involution).
template<int KLOOP, int KSTRIDE, bool GATHER, int EPI, int LOGC>
__global__ __launch_bounds__(512, 2) void gemm8_kernel(
    const u16* __restrict__ A, const u16* __restrict__ Bm,
    const float* __restrict__ bias, const int* __restrict__ tok_list,
    const float* __restrict__ gate_list, const int* __restrict__ counts,
    const int* __restrict__ offsets, const int* __restrict__ slots,
    int Ncols, u16* __restrict__ OutBf, float* __restrict__ outF,
    u16* __restrict__ outP) {
  constexpr int NT = KLOOP / 64;
  int gid = blockIdx.x;
  int q = gid >> 3;
  constexpr int PERX = 9 << LOGC;
  int kq = q / PERX;
  int r0q = q - kq * PERX;
  int slot = (gid & 7) * 9 + (r0q >> LOGC);
  int ct = r0q & ((1 << LOGC) - 1);
  int packed = slots[slot];
  if (packed < 0) return;
  int e = packed >> 16;
  int rt = packed & 0xffff;
  int cnt = counts[e];
  int off = offsets[e];
  int col0 = ct * 256;
  int k0e = kq * KLOOP;   // element offset of this K-slice

  __shared__ __attribute__((aligned(16))) char ldsc[131072];  // A 64K | B 64K

  int tid = threadIdx.x;
  int w = tid >> 6, l = tid & 63;
  int wm = w >> 2, wn = w & 3;            // 2 x 4 wave grid
  int fr = l & 15, hi = l >> 4;
  int kk16 = hi << 4;
  int xr = (fr & 7) << 4;

  int rl0 = w * 8 + (l >> 3);
  int slotE = ((l & 7) ^ ((l >> 3) & 7)) << 3;  // pre-swizzled 8-elem slot
  const u16* aptr[4];
  const u16* bptr[4];
#pragma unroll
  for (int i = 0; i < 4; i++) {
    int r = rt * 256 + rl0 + i * 64;
    if (GATHER) {
      int idx = min(off + r, NASG - 1);
      aptr[i] = A + (size_t)tok_list[idx] * KSTRIDE + k0e + slotE;
    } else {
      aptr[i] = A + (size_t)(off + r) * KSTRIDE + k0e + slotE;
    }
    bptr[i] = Bm + ((size_t)e * Ncols + col0 + rl0 + i * 64) * KSTRIDE + k0e + slotE;
  }
  char* ldsA = ldsc;
  char* ldsB = ldsc + 65536;

  auto issueAB = [&](int t) {
    char* db = ldsB + (t & 1) * 32768 + w * 1024;
    char* da = ldsA + (t & 1) * 32768 + w * 1024;
    glds16(bptr[0] + t * 64, db);
    glds16(bptr[1] + t * 64, db + 8192);
    glds16(bptr[2] + t * 64, db + 16384);
    glds16(bptr[3] + t * 64, db + 24576);
    glds16(aptr[0] + t * 64, da);
    glds16(aptr[1] + t * 64, da + 8192);
    glds16(aptr[2] + t * 64, da + 16384);
    glds16(aptr[3] + t * 64, da + 24576);
  };

  f32x4 acc[8][4];
#pragma unroll
  for (int m = 0; m < 8; m++)
#pragma unroll
    for (int n = 0; n < 4; n++) acc[m][n] = (f32x4){0.f, 0.f, 0.f, 0.f};
  bf16x8 aF[4][2], bF0[2][2], bF1[2][2];

  // prologue: stage tile 0; drain; barrier
  issueAB(0);
  VMCNT0();
  BAR();

  for (int t = 0; t < NT; t++) {
    int abase = (t & 1) * 32768;
    int bbase = 65536 + (t & 1) * 32768;
    // depth-1 prefetch into parity (t+1)&1 (its last readers R(t-1) drained)
    if (t + 1 < NT) issueAB(t + 1);
    // read A-lo + all B fragments
#pragma unroll
    for (int mm = 0; mm < 4; mm++)
#pragma unroll
      for (int ks = 0; ks < 2; ks++)
        aF[mm][ks] = *(const bf16x8*)(ldsc + abase + (wm * 128 + mm * 16 + fr) * 128 +
                                      ((ks * 64 + kk16) ^ xr));
#pragma unroll
    for (int nn = 0; nn < 2; nn++)
#pragma unroll
      for (int ks = 0; ks < 2; ks++) {
        bF0[nn][ks] = *(const bf16x8*)(ldsc + bbase + (wn * 64 + nn * 16 + fr) * 128 +
                                       ((ks * 64 + kk16) ^ xr));
        bF1[nn][ks] = *(const bf16x8*)(ldsc + bbase + (wn * 64 + 32 + nn * 16 + fr) * 128 +
                                       ((ks * 64 + kk16) ^ xr));
      }
    __builtin_amdgcn_s_setprio(1);
    // MFMA-lo with per-group aHi refill: after the 8 MFMAs consuming aF[mm],
    // immediately reload aF[mm] from the hi row; sched_barrier pins placement.
#pragma unroll
    for (int mm = 0; mm < 4; mm++) {
#pragma unroll
      for (int nn = 0; nn < 2; nn++)
#pragma unroll
        for (int ks = 0; ks < 2; ks++) {
          acc[mm][nn]     = __builtin_amdgcn_mfma_f32_16x16x32_bf16(aF[mm][ks], bF0[nn][ks], acc[mm][nn], 0, 0, 0);
          acc[mm][2 + nn] = __builtin_amdgcn_mfma_f32_16x16x32_bf16(aF[mm][ks], bF1[nn][ks], acc[mm][2 + nn], 0, 0, 0);
        }
      __builtin_amdgcn_sched_barrier(0);
#pragma unroll
      for (int ks = 0; ks < 2; ks++)
        aF[mm][ks] = *(const bf16x8*)(ldsc + abase + (wm * 128 + 64 + mm * 16 + fr) * 128 +
                                      ((ks * 64 + kk16) ^ xr));
      __builtin_amdgcn_sched_barrier(0);
    }
    // MFMA-hi (aF now holds hi rows; refills completed under MFMA-lo)
#pragma unroll
    for (int mm = 0; mm < 4; mm++)
#pragma unroll
      for (int nn = 0; nn < 2; nn++)
#pragma unroll
        for (int ks = 0; ks < 2; ks++) {
          acc[4 + mm][nn]     = __builtin_amdgcn_mfma_f32_16x16x32_bf16(aF[mm][ks], bF0[nn][ks], acc[4 + mm][nn], 0, 0, 0);
          acc[4 + mm][2 + nn] = __builtin_amdgcn_mfma_f32_16x16x32_bf16(aF[mm][ks], bF1[nn][ks], acc[4 + mm][2 + nn], 0, 0, 0);
        }
    __builtin_amdgcn_s_setprio(0);
    // drain own glds(t+1) (issued ~4000 cyc ago -> ~no stall) and sync
    VMCNT0();
    BAR();
  }

  // ---- epilogue
  float biasN[4];
  int cN[4];
#pragma unroll
  for (int n = 0; n < 4; n++) {
    cN[n] = col0 + wn * 64 + (n >> 1) * 32 + (n & 1) * 16 + fr;
    biasN[n] = (EPI == 2) ? 0.f : bias[e * Ncols + cN[n]];
  }
  if constexpr (EPI == 0) {
#pragma unroll
    for (int m = 0; m < 8; m++) {
      int rb = rt * 256 + wm * 128 + (m >> 2) * 64 + (m & 3) * 16 + hi * 4;
#pragma unroll
      for (int j = 0; j < 4; j++) {
        int r = rb + j;
        if (r < cnt) {
#pragma unroll
          for (int n = 0; n < 4; n++) {
            float v = acc[m][n][j] + biasN[n];
            OutBf[(size_t)(off + r) * Ncols + cN[n]] = f2bf(fmaxf(v, 0.f));
          }
        }
      }
    }
  } else if constexpr (EPI == 1) {
#pragma unroll
    for (int m = 0; m < 8; m++) {
      int rb = rt * 256 + wm * 128 + (m >> 2) * 64 + (m & 3) * 16 + hi * 4;
#pragma unroll
      for (int j = 0; j < 4; j++) {
        int r = rb + j;
        if (r < cnt) {
          int idx = off + r;
          int tok = tok_list[idx];
          float g = gate_list[idx];
          size_t erow = ((size_t)e * TKN + tok) * DD;
#pragma unroll
          for (int n = 0; n < 4; n++)
            outF[erow + cN[n]] = (acc[m][n][j] + biasN[n]) * g;
        }
      }
    }
  } else {
    // bf16 K-partial: outP[kq][asg][DD]
#pragma unroll
    for (int m = 0; m < 8; m++) {
      int rb = rt * 256 + wm * 128 + (m >> 2) * 64 + (m & 3) * 16 + hi * 4;
#pragma unroll
      for (int j = 0; j < 4; j++) {
        int r = rb + j;
        if (r < cnt) {
          size_t prow = ((size_t)kq * NASG + off + r) * DD;
#pragma unroll
          for (int n = 0; n < 4; n++)
            outP[prow + cN[n]] = f2bf(acc[m][n][j]);
        }
      }
    }
  }
}

extern "C" void kernel_launch(void* const* d_in, const int* in_sizes, int n_in,
                              void* d_out, int out_size, void* d_ws, size_t ws_size,
                              hipStream_t stream) {
  const float* x     = (const float*)d_in[0];
  const float* noise = (const float*)d_in[1];
  const float* Wg    = (const float*)d_in[2];
  const float* bg    = (const float*)d_in[3];
  const float* Wn    = (const float*)d_in[4];
  const float* bn    = (const float*)d_in[5];
  const float* W1    = (const float*)d_in[6];
  const float* b1    = (const float*)d_in[7];
  const float* W2    = (const float*)d_in[8];
  const float* b2    = (const float*)d_in[9];

  float* final_out  = (float*)d_out;
  float* expert_out = final_out + (size_t)TKN * DD;
  float* gating     = expert_out + (size_t)EE * TKN * DD;

  char* ws = (char*)d_ws;
  size_t o = 0;
  auto alloc = [&](size_t bytes) {
    char* p = ws + o;
    o += bytes;
    o = (o + 255) & ~(size_t)255;
    return p;
  };
  u16*   xb        = (u16*)alloc((size_t)TKN * DD * 2);
  u16*   w1t       = (u16*)alloc((size_t)EE * HH * DD * 2);        // [E][H][D]
  u16*   w2t       = (u16*)alloc((size_t)EE * DD * HH * 2);        // [E][D][H]
  u16*   hbuf      = (u16*)alloc(((size_t)NASG + 256) * HH * 2);   // +256 pad rows
  int*   tok_list  = (int*)alloc((size_t)NASG * 4);
  float* gate_list = (float*)alloc((size_t)NASG * 4);
  int*   sel_e     = (int*)alloc((size_t)NASG * 4);
  float* sel_g     = (float*)alloc((size_t)NASG * 4);
  int*   asg_of    = (int*)alloc((size_t)NASG * 4);
  int*   counts    = (int*)alloc(256);
  int*   offsets   = (int*)alloc(256);
  int*   cursors   = (int*)alloc(256);
  int*   slots     = (int*)alloc(NSLOT * 4);
  u16*   part      = (u16*)alloc((size_t)4 * NASG * DD * 2);       // 134 MB (last)
  bool use_split = (o <= ws_size);

  // zero only gating (router writes just the top-2 entries per token)
  hipMemsetAsync(gating, 0, (size_t)TKN * EE * sizeof(float), stream);

  router_kernel<<<TKN, 256, 0, stream>>>(x, noise, Wg, bg, Wn, bn, gating, xb, sel_e, sel_g);
  hist_scan_kernel<<<1, 256, 0, stream>>>(sel_e, counts, offsets, cursors, slots);
  build_lists_kernel<<<TKN / 256, 256, 0, stream>>>(sel_e, sel_g, cursors, tok_list,
                                                    gate_list, asg_of);
  // zero only the non-selected expert_out rows (gate==0 <=> not selected)
  zerofill_kernel<<<EE * TKN, 256, 0, stream>>>(gating, expert_out);

  transpose_cvt_kernel<<<dim3(HH / 32, DD / 64, EE), dim3(32, 8), 0, stream>>>(W1, w1t, DD, HH);
  transpose_cvt_kernel<<<dim3(DD / 32, HH / 64, EE), dim3(32, 8), 0, stream>>>(W2, w2t, HH, DD);

  // GEMM1: h = relu(x[tok] @ W1[e] + b1), K=1024, N=4096; 16 col-tiles
  gemm8_kernel<DD, DD, true, 0, 4><<<8 * 9 * 16, 512, 0, stream>>>(
      xb, w1t, b1, tok_list, nullptr, counts, offsets, slots, HH, hbuf, nullptr, nullptr);

  if (use_split) {
    // GEMM2 split-K x4: bf16 partials, then merge(+bias,gate)+combine per token
    gemm8_kernel<HH / 4, HH, false, 2, 2><<<8 * 9 * 4 * 4, 512, 0, stream>>>(
        hbuf, w2t, b2, tok_list, gate_list, counts, offsets, slots, DD, nullptr, nullptr, part);
    merge_combine_kernel<<<TKN, 256, 0, stream>>>(part, asg_of, sel_e, sel_g, b2,
                                                  expert_out, final_out);
  } else {
    // fallback: single-shot GEMM2 + combine
    gemm8_kernel<HH, HH, false, 1, 2><<<8 * 9 * 4, 512, 0, stream>>>(
        hbuf, w2t, b2, tok_list, gate_list, counts, offsets, slots, DD, nullptr, expert_out, nullptr);
    combine_kernel<<<TKN, 256, 0, stream>>>(expert_out, sel_e, final_out);
  }
}

// Round 11
// 606.050 us; speedup vs baseline: 4.3206x; 1.0060x over previous
//
#include <hip/hip_runtime.h>
#include <hip/hip_bf16.h>
#include <stdint.h>

// Problem constants: B=8,S=1024,D=1024,E=8,H=4096,top_k=2
#define TKN   8192
#define DD    1024
#define EE    8
#define HH    4096
#define TOPK  2
#define NASG  (TKN * TOPK)      // 16384 assignments
#define NSLOT 72                // >= sum_e ceil(cnt_e/256) (<= 64+7)

typedef unsigned short u16;
typedef __bf16 bf16x8 __attribute__((ext_vector_type(8)));
typedef float  f32x4  __attribute__((ext_vector_type(4)));

__device__ __forceinline__ u16 f2bf(float f) {
  __hip_bfloat16 h = __float2bfloat16(f);
  return __builtin_bit_cast(u16, h);
}
__device__ __forceinline__ float bf2f(u16 u) {
  uint32_t v = ((uint32_t)u) << 16;
  return __builtin_bit_cast(float, v);
}

__device__ __forceinline__ void glds16(const void* g, void* l) {
  __builtin_amdgcn_global_load_lds(
      (__attribute__((address_space(1))) void*)g,
      (__attribute__((address_space(3))) void*)l, 16, 0, 0);
}

#define FENCE() asm volatile("" ::: "memory")
#define BAR()   do { FENCE(); __builtin_amdgcn_s_barrier(); FENCE(); } while (0)
#define VMCNT0() asm volatile("s_waitcnt vmcnt(0)" ::: "memory")

// ---------------- transpose + f32->bf16: [E][R][C] f32 -> [E][C][R] bf16
__global__ __launch_bounds__(256) void transpose_cvt_kernel(
    const float* __restrict__ src, u16* __restrict__ dst, int R, int C) {
  __shared__ float tile[64][33];
  int e = blockIdx.z;
  int c0 = blockIdx.x * 32, r0 = blockIdx.y * 64;
  int tx = threadIdx.x, ty = threadIdx.y;  // 32 x 8
  const float* s = src + (size_t)e * R * C;
  uint32_t* d32 = (uint32_t*)(dst + (size_t)e * R * C);
#pragma unroll
  for (int j = 0; j < 8; j++)
    tile[ty * 8 + j][tx] = s[(size_t)(r0 + ty * 8 + j) * C + c0 + tx];
  __syncthreads();
#pragma unroll
  for (int jj = 0; jj < 4; jj++) {
    int c = c0 + ty * 4 + jj;
    uint32_t lo = f2bf(tile[2 * tx][ty * 4 + jj]);
    uint32_t hi = f2bf(tile[2 * tx + 1][ty * 4 + jj]);
    d32[((size_t)c * R + r0) / 2 + tx] = lo | (hi << 16);
  }
}

// ---------------- router (writes the FULL 8-wide gating row; no memset needed)
__global__ __launch_bounds__(256) void router_kernel(
    const float* __restrict__ x, const float* __restrict__ noise,
    const float* __restrict__ Wg, const float* __restrict__ bg,
    const float* __restrict__ Wn, const float* __restrict__ bn,
    float* __restrict__ gating, u16* __restrict__ xb,
    int* __restrict__ sel_e, float* __restrict__ sel_g) {
  int t = blockIdx.x;
  int tid = threadIdx.x;
  float acc[16];
#pragma unroll
  for (int j = 0; j < 16; j++) acc[j] = 0.f;
  for (int i = tid; i < DD; i += 256) {
    float xv = x[(size_t)t * DD + i];
    xb[(size_t)t * DD + i] = f2bf(xv);
    const float4* g4 = (const float4*)(Wg + (size_t)i * EE);
    const float4* n4 = (const float4*)(Wn + (size_t)i * EE);
    float4 ga = g4[0], gb = g4[1];
    float4 na = n4[0], nb = n4[1];
    acc[0] += xv * ga.x;  acc[1] += xv * ga.y;  acc[2] += xv * ga.z;  acc[3] += xv * ga.w;
    acc[4] += xv * gb.x;  acc[5] += xv * gb.y;  acc[6] += xv * gb.z;  acc[7] += xv * gb.w;
    acc[8] += xv * na.x;  acc[9] += xv * na.y;  acc[10] += xv * na.z; acc[11] += xv * na.w;
    acc[12] += xv * nb.x; acc[13] += xv * nb.y; acc[14] += xv * nb.z; acc[15] += xv * nb.w;
  }
  __shared__ float red[4][16];
  int lane = tid & 63, wv = tid >> 6;
#pragma unroll
  for (int j = 0; j < 16; j++) {
    float v = acc[j];
    for (int o = 32; o > 0; o >>= 1) v += __shfl_down(v, o);
    acc[j] = v;
  }
  if (lane == 0) {
#pragma unroll
    for (int j = 0; j < 16; j++) red[wv][j] = acc[j];
  }
  __syncthreads();
  if (tid == 0) {
    float nz[EE];
#pragma unroll
    for (int e = 0; e < EE; e++) {
      float dg = red[0][e] + red[1][e] + red[2][e] + red[3][e] + bg[e];
      float dn = red[0][8 + e] + red[1][8 + e] + red[2][8 + e] + red[3][8 + e] + bn[e];
      float sp = fmaxf(dn, 0.f) + log1pf(expf(-fabsf(dn)));
      nz[e] = dg + noise[(size_t)t * EE + e] * sp;
    }
    int m1 = 0;
    for (int e = 1; e < EE; e++) if (nz[e] > nz[m1]) m1 = e;
    int m2 = (m1 == 0) ? 1 : 0;
    for (int e = 0; e < EE; e++) if (e != m1 && nz[e] > nz[m2]) m2 = e;
    float eb = expf(nz[m2] - nz[m1]);
    float den = 1.f + eb;
    float g1 = 1.f / den, g2 = eb / den;
#pragma unroll
    for (int e = 0; e < EE; e++)
      gating[(size_t)t * EE + e] = (e == m1) ? g1 : (e == m2) ? g2 : 0.f;
    sel_e[t * 2] = m1; sel_e[t * 2 + 1] = m2;
    sel_g[t * 2] = g1; sel_g[t * 2 + 1] = g2;
  }
}

// ---------------- histogram + scan + slot table (1 block)
__global__ __launch_bounds__(256) void hist_scan_kernel(
    const int* __restrict__ sel_e, int* __restrict__ counts,
    int* __restrict__ offsets, int* __restrict__ cursors,
    int* __restrict__ slots) {
  __shared__ int hist[EE];
  int tid = threadIdx.x;
  if (tid < EE) hist[tid] = 0;
  __syncthreads();
  for (int i = tid; i < NASG; i += 256) atomicAdd(&hist[sel_e[i]], 1);
  __syncthreads();
  if (tid == 0) {
    int off = 0, ns = 0;
    for (int e = 0; e < EE; e++) {
      int c = hist[e];
      counts[e] = c; offsets[e] = off; cursors[e] = off; off += c;
      int nrt = (c + 255) >> 8;
      for (int rt = 0; rt < nrt; rt++) slots[ns++] = (e << 16) | rt;
    }
    for (; ns < NSLOT; ns++) slots[ns] = -1;
  }
}

// ---------------- build per-expert token lists (+ token->assignment-slot map)
__global__ __launch_bounds__(256) void build_lists_kernel(
    const int* __restrict__ sel_e, const float* __restrict__ sel_g,
    int* __restrict__ cursors, int* __restrict__ tok_list,
    float* __restrict__ gate_list, int* __restrict__ asg_of) {
  int t = blockIdx.x * 256 + threadIdx.x;
  int lane = threadIdx.x & 63;
#pragma unroll
  for (int k = 0; k < TOPK; k++) {
    int e = sel_e[t * 2 + k];
    float g = sel_g[t * 2 + k];
    for (int ee = 0; ee < EE; ee++) {
      unsigned long long m = __ballot(e == ee);
      if (m) {
        int leader = __ffsll(m) - 1;
        int base = 0;
        if (lane == leader) base = atomicAdd(&cursors[ee], __popcll(m));
        base = __shfl(base, leader);
        if (e == ee) {
          int slot = base + __popcll(m & ((1ull << lane) - 1ull));
          tok_list[slot] = t;
          gate_list[slot] = g;
          asg_of[t * 2 + k] = slot;
        }
      }
    }
  }
}

// ---------------- zero-fill non-selected expert_out rows (fallback path only)
__global__ __launch_bounds__(256) void zerofill_kernel(
    const float* __restrict__ gating, float* __restrict__ expert_out) {
  int id = blockIdx.x;              // 0 .. EE*TKN-1
  int e = id >> 13, t = id & (TKN - 1);
  if (gating[(size_t)t * EE + e] != 0.f) return;
  float4* p = (float4*)(expert_out + ((size_t)e * TKN + t) * DD);
  p[threadIdx.x] = (float4){0.f, 0.f, 0.f, 0.f};
}

// ---------------- combine (fallback path): final = expert rows sum
__global__ __launch_bounds__(256) void combine_kernel(
    const float* __restrict__ expert_out, const int* __restrict__ sel_e,
    float* __restrict__ final_out) {
  int t = blockIdx.x;
  int e1 = sel_e[2 * t], e2 = sel_e[2 * t + 1];
  const float4* r1 = (const float4*)(expert_out + ((size_t)e1 * TKN + t) * DD);
  const float4* r2 = (const float4*)(expert_out + ((size_t)e2 * TKN + t) * DD);
  float4* o = (float4*)(final_out + (size_t)t * DD);
  int i = threadIdx.x;
  float4 a = r1[i], b = r2[i];
  o[i] = (float4){a.x + b.x, a.y + b.y, a.z + b.z, a.w + b.w};
}

// ---------------- finalize: merge 4 bf16 K-partials + bias + gate, write ALL
// 8 expert rows per token (zeros for non-selected) + final. Replaces
// zerofill + merge_combine (one pass, same traffic, fewer launches).
__global__ __launch_bounds__(256) void finalize_kernel(
    const u16* __restrict__ part, const int* __restrict__ asg_of,
    const int* __restrict__ sel_e, const float* __restrict__ sel_g,
    const float* __restrict__ b2, float* __restrict__ expert_out,
    float* __restrict__ final_out) {
  int t = blockIdx.x;
  int i = threadIdx.x;
  int i1 = asg_of[2 * t], i2 = asg_of[2 * t + 1];
  int e1 = sel_e[2 * t], e2 = sel_e[2 * t + 1];
  float g1 = sel_g[2 * t], g2 = sel_g[2 * t + 1];
  float s1[4] = {0.f, 0.f, 0.f, 0.f}, s2[4] = {0.f, 0.f, 0.f, 0.f};
#pragma unroll
  for (int kq = 0; kq < 4; kq++) {
    ushort4 a = ((const ushort4*)(part + ((size_t)kq * NASG + i1) * DD))[i];
    ushort4 b = ((const ushort4*)(part + ((size_t)kq * NASG + i2) * DD))[i];
    s1[0] += bf2f(a.x); s1[1] += bf2f(a.y); s1[2] += bf2f(a.z); s1[3] += bf2f(a.w);
    s2[0] += bf2f(b.x); s2[1] += bf2f(b.y); s2[2] += bf2f(b.z); s2[3] += bf2f(b.w);
  }
  float4 bb1 = ((const float4*)(b2 + (size_t)e1 * DD))[i];
  float4 bb2 = ((const float4*)(b2 + (size_t)e2 * DD))[i];
  float4 y1 = {(s1[0] + bb1.x) * g1, (s1[1] + bb1.y) * g1,
               (s1[2] + bb1.z) * g1, (s1[3] + bb1.w) * g1};
  float4 y2 = {(s2[0] + bb2.x) * g2, (s2[1] + bb2.y) * g2,
               (s2[2] + bb2.z) * g2, (s2[3] + bb2.w) * g2};
  float4 z = {0.f, 0.f, 0.f, 0.f};
#pragma unroll
  for (int e = 0; e < EE; e++) {
    float4 v = (e == e1) ? y1 : (e == e2) ? y2 : z;
    ((float4*)(expert_out + ((size_t)e * TKN + t) * DD))[i] = v;
  }
  ((float4*)(final_out + (size_t)t * DD))[i] =
      (float4){y1.x + y2.x, y1.y + y2.y, y1.z + y2.z, y1.w + y2.w};
}

// ---------------- 256x256 / BK=64 / 8-wave grouped GEMM, 1-barrier-per-tile,
// CROSS-BARRIER WAVE-GROUP STAGGER.
// Group 0 (waves 0-3, wm=0): per tile: issueAB(t+1); R_lo+B(t); M_lo(t);
//   R_hi(t); M_hi(t); vmcnt(0); bar.
// Group 1 (waves 4-7, wm=1): per tile: issueAB(t+1); M_hi(t-1) [DEFERRED
//   across the barrier]; R_lo+B(t); M_lo(t); R_hi(t); vmcnt(0); bar.
//   Tail M_hi(NT-1) after the loop.
// Mechanism: with all waves phase-locked by the per-tile barrier, LDS-read
// (2300cyc/CU) and MFMA (2483cyc/CU) phases were ADDING (5530 measured).
// The stagger puts one MFMA-issuing wave and one read-issuing wave on each
// SIMD in every half-phase -> pipes overlap. Register-legal with ZERO extra
// VGPRs: deferred M_hi reads exactly the aF/bF set that R(t) overwrites;
// the WAR dependence also pins the order against compiler reordering.
// M_hi is register-only, so executing it after the barrier is safe; barrier
// counts match (NT per wave on both paths); vmcnt(0)+bar protocol unchanged.
// EPI: 0 = relu->bf16 OutBf; 1 = (acc+bias)*gate -> f32 outF; 2 = bf16
// K-partial -> outP[kq][asg][DD].
// Decode (1-D grid, kq-outer within XCD): gid -> xcd=gid&7, q=gid>>3,
// kq=q/(9<<LOGC), r=q%(9<<LOGC), slot=xcd*9+(r>>LOGC), ct=r&mask.
// LDS swizzle: stored 16B chunk c of row r holds global chunk c^(r&7) —
// linear glds dest + inverse-swizzled per-lane global source (involution).
template<int KLOOP, int KSTRIDE, bool GATHER, int EPI, int LOGC>
__global__ __launch_bounds__(512, 2) void gemm8_kernel(
    const u16* __restrict__ A, const u16* __restrict__ Bm,
    const float* __restrict__ bias, const int* __restrict__ tok_list,
    const float* __restrict__ gate_list, const int* __restrict__ counts,
    const int* __restrict__ offsets, const int* __restrict__ slots,
    int Ncols, u16* __restrict__ OutBf, float* __restrict__ outF,
    u16* __restrict__ outP) {
  constexpr int NT = KLOOP / 64;
  int gid = blockIdx.x;
  int q = gid >> 3;
  constexpr int PERX = 9 << LOGC;
  int kq = q / PERX;
  int r0q = q - kq * PERX;
  int slot = (gid & 7) * 9 + (r0q >> LOGC);
  int ct = r0q & ((1 << LOGC) - 1);
  int packed = slots[slot];
  if (packed < 0) return;
  int e = packed >> 16;
  int rt = packed & 0xffff;
  int cnt = counts[e];
  int off = offsets[e];
  int col0 = ct * 256;
  int k0e = kq * KLOOP;   // element offset of this K-slice

  __shared__ __attribute__((aligned(16))) char ldsc[131072];  // A 64K | B 64K

  int tid = threadIdx.x;
  int w = tid >> 6, l = tid & 63;
  int wm = w >> 2, wn = w & 3;            // 2 x 4 wave grid; wm is also group
  int fr = l & 15, hi = l >> 4;
  int kk16 = hi << 4;
  int xr = (fr & 7) << 4;

  int rl0 = w * 8 + (l >> 3);
  int slotE = ((l & 7) ^ ((l >> 3) & 7)) << 3;  // pre-swizzled 8-elem slot
  const u16* aptr[4];
  const u16* bptr[4];
#pragma unroll
  for (int i = 0; i < 4; i++) {
    int r = rt * 256 + rl0 + i * 64;
    if (GATHER) {
      int idx = min(off + r, NASG - 1);
      aptr[i] = A + (size_t)tok_list[idx] * KSTRIDE + k0e + slotE;
    } else {
      aptr[i] = A + (size_t)(off + r) * KSTRIDE + k0e + slotE;
    }
    bptr[i] = Bm + ((size_t)e * Ncols + col0 + rl0 + i * 64) * KSTRIDE + k0e + slotE;
  }
  char* ldsA = ldsc;
  char* ldsB = ldsc + 65536;

  auto issueAB = [&](int t) {
    char* db = ldsB + (t & 1) * 32768 + w * 1024;
    char* da = ldsA + (t & 1) * 32768 + w * 1024;
    glds16(bptr[0] + t * 64, db);
    glds16(bptr[1] + t * 64, db + 8192);
    glds16(bptr[2] + t * 64, db + 16384);
    glds16(bptr[3] + t * 64, db + 24576);
    glds16(aptr[0] + t * 64, da);
    glds16(aptr[1] + t * 64, da + 8192);
    glds16(aptr[2] + t * 64, da + 16384);
    glds16(aptr[3] + t * 64, da + 24576);
  };

  f32x4 acc[8][4];
#pragma unroll
  for (int m = 0; m < 8; m++)
#pragma unroll
    for (int n = 0; n < 4; n++) acc[m][n] = (f32x4){0.f, 0.f, 0.f, 0.f};
  bf16x8 aF[4][2], bF0[2][2], bF1[2][2];

  auto RLOB = [&](int ab, int bb) {
#pragma unroll
    for (int mm = 0; mm < 4; mm++)
#pragma unroll
      for (int ks = 0; ks < 2; ks++)
        aF[mm][ks] = *(const bf16x8*)(ldsc + ab + (wm * 128 + mm * 16 + fr) * 128 +
                                      ((ks * 64 + kk16) ^ xr));
#pragma unroll
    for (int nn = 0; nn < 2; nn++)
#pragma unroll
      for (int ks = 0; ks < 2; ks++) {
        bF0[nn][ks] = *(const bf16x8*)(ldsc + bb + (wn * 64 + nn * 16 + fr) * 128 +
                                       ((ks * 64 + kk16) ^ xr));
        bF1[nn][ks] = *(const bf16x8*)(ldsc + bb + (wn * 64 + 32 + nn * 16 + fr) * 128 +
                                       ((ks * 64 + kk16) ^ xr));
      }
  };
  auto RHI = [&](int ab) {
#pragma unroll
    for (int mm = 0; mm < 4; mm++)
#pragma unroll
      for (int ks = 0; ks < 2; ks++)
        aF[mm][ks] = *(const bf16x8*)(ldsc + ab + (wm * 128 + 64 + mm * 16 + fr) * 128 +
                                      ((ks * 64 + kk16) ^ xr));
  };
  auto MLO = [&]() {
    __builtin_amdgcn_s_setprio(1);
#pragma unroll
    for (int mm = 0; mm < 4; mm++)
#pragma unroll
      for (int nn = 0; nn < 2; nn++)
#pragma unroll
        for (int ks = 0; ks < 2; ks++) {
          acc[mm][nn]     = __builtin_amdgcn_mfma_f32_16x16x32_bf16(aF[mm][ks], bF0[nn][ks], acc[mm][nn], 0, 0, 0);
          acc[mm][2 + nn] = __builtin_amdgcn_mfma_f32_16x16x32_bf16(aF[mm][ks], bF1[nn][ks], acc[mm][2 + nn], 0, 0, 0);
        }
    __builtin_amdgcn_s_setprio(0);
  };
  auto MHI = [&]() {
    __builtin_amdgcn_s_setprio(1);
#pragma unroll
    for (int mm = 0; mm < 4; mm++)
#pragma unroll
      for (int nn = 0; nn < 2; nn++)
#pragma unroll
        for (int ks = 0; ks < 2; ks++) {
          acc[4 + mm][nn]     = __builtin_amdgcn_mfma_f32_16x16x32_bf16(aF[mm][ks], bF0[nn][ks], acc[4 + mm][nn], 0, 0, 0);
          acc[4 + mm][2 + nn] = __builtin_amdgcn_mfma_f32_16x16x32_bf16(aF[mm][ks], bF1[nn][ks], acc[4 + mm][2 + nn], 0, 0, 0);
        }
    __builtin_amdgcn_s_setprio(0);
  };

  // prologue: stage tile 0; drain; barrier
  issueAB(0);
  VMCNT0();
  BAR();

  if (wm == 0) {
    // group 0: in-tile order
    for (int t = 0; t < NT; t++) {
      int ab = (t & 1) * 32768;
      int bb = 65536 + (t & 1) * 32768;
      if (t + 1 < NT) issueAB(t + 1);
      RLOB(ab, bb);
      MLO();
      RHI(ab);
      MHI();
      VMCNT0();
      BAR();
    }
  } else {
    // group 1: M_hi deferred across the barrier (stagger)
    for (int t = 0; t < NT; t++) {
      int ab = (t & 1) * 32768;
      int bb = 65536 + (t & 1) * 32768;
      if (t + 1 < NT) issueAB(t + 1);
      if (t > 0) MHI();          // tile t-1's hi half (registers only)
      RLOB(ab, bb);              // WAR on aF/bF pins this after MHI
      MLO();
      RHI(ab);
      VMCNT0();
      BAR();
    }
    MHI();                       // tail: tile NT-1's hi half
  }

  // ---- epilogue
  float biasN[4];
  int cN[4];
#pragma unroll
  for (int n = 0; n < 4; n++) {
    cN[n] = col0 + wn * 64 + (n >> 1) * 32 + (n & 1) * 16 + fr;
    biasN[n] = (EPI == 2) ? 0.f : bias[e * Ncols + cN[n]];
  }
  if constexpr (EPI == 0) {
#pragma unroll
    for (int m = 0; m < 8; m++) {
      int rb = rt * 256 + wm * 128 + (m >> 2) * 64 + (m & 3) * 16 + hi * 4;
#pragma unroll
      for (int j = 0; j < 4; j++) {
        int r = rb + j;
        if (r < cnt) {
#pragma unroll
          for (int n = 0; n < 4; n++) {
            float v = acc[m][n][j] + biasN[n];
            OutBf[(size_t)(off + r) * Ncols + cN[n]] = f2bf(fmaxf(v, 0.f));
          }
        }
      }
    }
  } else if constexpr (EPI == 1) {
#pragma unroll
    for (int m = 0; m < 8; m++) {
      int rb = rt * 256 + wm * 128 + (m >> 2) * 64 + (m & 3) * 16 + hi * 4;
#pragma unroll
      for (int j = 0; j < 4; j++) {
        int r = rb + j;
        if (r < cnt) {
          int idx = off + r;
          int tok = tok_list[idx];
          float g = gate_list[idx];
          size_t erow = ((size_t)e * TKN + tok) * DD;
#pragma unroll
          for (int n = 0; n < 4; n++)
            outF[erow + cN[n]] = (acc[m][n][j] + biasN[n]) * g;
        }
      }
    }
  } else {
    // bf16 K-partial: outP[kq][asg][DD]
#pragma unroll
    for (int m = 0; m < 8; m++) {
      int rb = rt * 256 + wm * 128 + (m >> 2) * 64 + (m & 3) * 16 + hi * 4;
#pragma unroll
      for (int j = 0; j < 4; j++) {
        int r = rb + j;
        if (r < cnt) {
          size_t prow = ((size_t)kq * NASG + off + r) * DD;
#pragma unroll
          for (int n = 0; n < 4; n++)
            outP[prow + cN[n]] = f2bf(acc[m][n][j]);
        }
      }
    }
  }
}

extern "C" void kernel_launch(void* const* d_in, const int* in_sizes, int n_in,
                              void* d_out, int out_size, void* d_ws, size_t ws_size,
                              hipStream_t stream) {
  const float* x     = (const float*)d_in[0];
  const float* noise = (const float*)d_in[1];
  const float* Wg    = (const float*)d_in[2];
  const float* bg    = (const float*)d_in[3];
  const float* Wn    = (const float*)d_in[4];
  const float* bn    = (const float*)d_in[5];
  const float* W1    = (const float*)d_in[6];
  const float* b1    = (const float*)d_in[7];
  const float* W2    = (const float*)d_in[8];
  const float* b2    = (const float*)d_in[9];

  float* final_out  = (float*)d_out;
  float* expert_out = final_out + (size_t)TKN * DD;
  float* gating     = expert_out + (size_t)EE * TKN * DD;

  char* ws = (char*)d_ws;
  size_t o = 0;
  auto alloc = [&](size_t bytes) {
    char* p = ws + o;
    o += bytes;
    o = (o + 255) & ~(size_t)255;
    return p;
  };
  u16*   xb        = (u16*)alloc((size_t)TKN * DD * 2);
  u16*   w1t       = (u16*)alloc((size_t)EE * HH * DD * 2);        // [E][H][D]
  u16*   w2t       = (u16*)alloc((size_t)EE * DD * HH * 2);        // [E][D][H]
  u16*   hbuf      = (u16*)alloc(((size_t)NASG + 256) * HH * 2);   // +256 pad rows
  int*   tok_list  = (int*)alloc((size_t)NASG * 4);
  float* gate_list = (float*)alloc((size_t)NASG * 4);
  int*   sel_e     = (int*)alloc((size_t)NASG * 4);
  float* sel_g     = (float*)alloc((size_t)NASG * 4);
  int*   asg_of    = (int*)alloc((size_t)NASG * 4);
  int*   counts    = (int*)alloc(256);
  int*   offsets   = (int*)alloc(256);
  int*   cursors   = (int*)alloc(256);
  int*   slots     = (int*)alloc(NSLOT * 4);
  u16*   part      = (u16*)alloc((size_t)4 * NASG * DD * 2);       // 134 MB (last)
  bool use_split = (o <= ws_size);

  router_kernel<<<TKN, 256, 0, stream>>>(x, noise, Wg, bg, Wn, bn, gating, xb, sel_e, sel_g);
  hist_scan_kernel<<<1, 256, 0, stream>>>(sel_e, counts, offsets, cursors, slots);
  build_lists_kernel<<<TKN / 256, 256, 0, stream>>>(sel_e, sel_g, cursors, tok_list,
                                                    gate_list, asg_of);

  transpose_cvt_kernel<<<dim3(HH / 32, DD / 64, EE), dim3(32, 8), 0, stream>>>(W1, w1t, DD, HH);
  transpose_cvt_kernel<<<dim3(DD / 32, HH / 64, EE), dim3(32, 8), 0, stream>>>(W2, w2t, HH, DD);

  // GEMM1: h = relu(x[tok] @ W1[e] + b1), K=1024, N=4096; 16 col-tiles
  gemm8_kernel<DD, DD, true, 0, 4><<<8 * 9 * 16, 512, 0, stream>>>(
      xb, w1t, b1, tok_list, nullptr, counts, offsets, slots, HH, hbuf, nullptr, nullptr);

  if (use_split) {
    // GEMM2 split-K x4: bf16 partials, then fused finalize (merge + zeros + final)
    gemm8_kernel<HH / 4, HH, false, 2, 2><<<8 * 9 * 4 * 4, 512, 0, stream>>>(
        hbuf, w2t, b2, tok_list, gate_list, counts, offsets, slots, DD, nullptr, nullptr, part);
    finalize_kernel<<<TKN, 256, 0, stream>>>(part, asg_of, sel_e, sel_g, b2,
                                             expert_out, final_out);
  } else {
    // fallback: single-shot GEMM2 + zerofill + combine
    zerofill_kernel<<<EE * TKN, 256, 0, stream>>>(gating, expert_out);
    gemm8_kernel<HH, HH, false, 1, 2><<<8 * 9 * 4, 512, 0, stream>>>(
        hbuf, w2t, b2, tok_list, gate_list, counts, offsets, slots, DD, nullptr, expert_out, nullptr);
    combine_kernel<<<TKN, 256, 0, stream>>>(expert_out, sel_e, final_out);
  }
}